// Round 1
// baseline (1425.105 us; speedup 1.0000x reference)
//
#include <hip/hip_runtime.h>
#include <hip/hip_bf16.h>
#include <math.h>

// ---------------- model constants ----------------
#define T_LEN 1024
#define HID 1024
#define NHEAD 32
#define HDIM 64         // P
#define NSTATE 128      // N
#define NLVL 15
#define KCONV 4
#define INTER 2048
#define CONV_DIM 2304   // INTER + 2*N
#define PROJ 4864       // INTER + CONV_DIM + H*(NL+1)
#define EPS 1e-5f

__device__ __forceinline__ float softplus_f(float x) {
  // log(1+e^x), stable both sides
  return fmaxf(x, 0.f) + log1pf(expf(-fabsf(x)));
}
__device__ __forceinline__ float silu_f(float x) {
  return x / (1.f + expf(-x));
}

// ---------------- GEMM: C[m,n] = sum_k A[m,k]*B[n,k] + bias[n] ----------------
// A: (M,K) row-major; B: (N,K) row-major (i.e. weight [out,in]); C: (M,N)
// M,N multiples of 64; K multiple of 16.
__global__ __launch_bounds__(256) void gemm_nt(
    const float* __restrict__ A, const float* __restrict__ B,
    const float* __restrict__ bias, float* __restrict__ C,
    int M, int N, int K) {
  __shared__ float As[16][65];   // [k][m]
  __shared__ float Bs[16][65];   // [k][n]
  const int tid = threadIdx.x;
  const int tx = tid & 15;       // n-group
  const int ty = tid >> 4;       // m-group
  const int m0 = blockIdx.y * 64;
  const int n0 = blockIdx.x * 64;
  float acc[4][4] = {};
  for (int kk = 0; kk < K; kk += 16) {
    for (int i = tid; i < 64 * 16; i += 256) {
      int r = i >> 4, c = i & 15;
      As[c][r] = A[(size_t)(m0 + r) * K + kk + c];
    }
    for (int i = tid; i < 64 * 16; i += 256) {
      int r = i >> 4, c = i & 15;
      Bs[c][r] = B[(size_t)(n0 + r) * K + kk + c];
    }
    __syncthreads();
#pragma unroll
    for (int k = 0; k < 16; ++k) {
      float a[4], b[4];
#pragma unroll
      for (int i = 0; i < 4; ++i) a[i] = As[k][ty * 4 + i];
#pragma unroll
      for (int j = 0; j < 4; ++j) b[j] = Bs[k][tx * 4 + j];
#pragma unroll
      for (int i = 0; i < 4; ++i)
#pragma unroll
        for (int j = 0; j < 4; ++j) acc[i][j] += a[i] * b[j];
    }
    __syncthreads();
  }
#pragma unroll
  for (int i = 0; i < 4; ++i) {
    int m = m0 + ty * 4 + i;
#pragma unroll
    for (int j = 0; j < 4; ++j) {
      int n = n0 + tx * 4 + j;
      C[(size_t)m * N + n] = acc[i][j] + bias[n];
    }
  }
}

// ---------------- per-token pointwise: dt, g, level scales ----------------
__global__ __launch_bounds__(512) void pointwise_dt(
    const float* __restrict__ zx, const float* __restrict__ dt_bias,
    const float* __restrict__ A_log, const float* __restrict__ L_param,
    float* __restrict__ dtbuf, float* __restrict__ gbuf,
    float* __restrict__ Lsbuf) {
  const int t = blockIdx.x;
  const int j = threadIdx.x;   // 512
  const float* row = zx + (size_t)t * PROJ;
  if (j < NHEAD * NLVL) {
    // j = h*15 + l
    float x = L_param[j] * row[INTER + CONV_DIM + NHEAD + j];
    Lsbuf[(size_t)t * (NHEAD * NLVL) + j] = softplus_f(x);
  } else {
    int h = j - NHEAD * NLVL;   // 0..31
    float x = row[INTER + CONV_DIM + h] + dt_bias[h];
    float dt = softplus_f(x);
    dtbuf[t * NHEAD + h] = dt;
    gbuf[t * NHEAD + h] = -expf(A_log[h]) * dt;
  }
}

// ---------------- depthwise causal conv (K=4) + SiLU + split/scale ----------------
__global__ __launch_bounds__(256) void conv_silu(
    const float* __restrict__ zx, const float* __restrict__ conv_w,
    const float* __restrict__ dtbuf, const float* __restrict__ Dp,
    float* __restrict__ vbuf, float* __restrict__ ybuf,
    float* __restrict__ Bbuf, float* __restrict__ Cbuf) {
  int idx = blockIdx.x * 256 + threadIdx.x;
  if (idx >= T_LEN * CONV_DIM) return;
  int t = idx / CONV_DIM;
  int c = idx - t * CONV_DIM;
  float acc = 0.f;
#pragma unroll
  for (int w = 0; w < KCONV; ++w) {
    int tt = t - (KCONV - 1) + w;
    if (tt >= 0) acc += zx[(size_t)tt * PROJ + INTER + c] * conv_w[c * KCONV + w];
  }
  float sil = silu_f(acc);
  if (c < INTER) {
    int h = c >> 6;
    float dt = dtbuf[t * NHEAD + h];
    vbuf[(size_t)t * INTER + c] = sil * dt;      // v = x*dt
    ybuf[(size_t)t * INTER + c] = sil * Dp[h];   // D residual (unscaled x * D)
  } else if (c < INTER + NSTATE) {
    Bbuf[t * NSTATE + (c - INTER)] = sil;
  } else {
    Cbuf[t * NSTATE + (c - INTER - NSTATE)] = sil;
  }
}

// ---------------- per-head inclusive cumsum of g over t ----------------
__global__ __launch_bounds__(1024) void scan_g(const float* __restrict__ gbuf,
                                               float* __restrict__ cg) {
  __shared__ float buf[T_LEN];
  const int h = blockIdx.x, t = threadIdx.x;
  buf[t] = gbuf[t * NHEAD + h];
  __syncthreads();
  for (int off = 1; off < T_LEN; off <<= 1) {
    float v = buf[t];
    float add = (t >= off) ? buf[t - off] : 0.f;
    __syncthreads();
    buf[t] = v + add;
    __syncthreads();
  }
  cg[h * T_LEN + t] = buf[t];
}

// ---------------- attention-like quadratic part ----------------
// grid: (16 query-tiles, 32 heads); block 256
// y[t,h,:] += sum_{s<=t} (C_t . B_s) * exp(cg[h,t]-cg[h,s]) * Ls[t,h,lvl(t,s)] * v[s,h,:]
__global__ __launch_bounds__(256) void attn_kernel(
    const float* __restrict__ Bbuf, const float* __restrict__ Cbuf,
    const float* __restrict__ vbuf, const float* __restrict__ cg,
    const float* __restrict__ Lsbuf, float* __restrict__ ybuf) {
  __shared__ float Cl[64][129];
  __shared__ float Bl[64][129];
  __shared__ float Vl[64][64];
  __shared__ float Sc[64][65];
  __shared__ float Lsl[64][NLVL];
  __shared__ float cgq[64];
  __shared__ float cgs[64];

  const int qt = blockIdx.x;
  const int h = blockIdx.y;
  const int tid = threadIdx.x;
  const int tq0 = qt * 64;

  for (int i = tid; i < 64 * 128; i += 256) {
    int r = i >> 7, c = i & 127;
    Cl[r][c] = Cbuf[(tq0 + r) * NSTATE + c];
  }
  for (int i = tid; i < 64 * NLVL; i += 256) {
    int r = i / NLVL, l = i - r * NLVL;
    Lsl[r][l] = Lsbuf[(size_t)(tq0 + r) * (NHEAD * NLVL) + h * NLVL + l];
  }
  if (tid < 64) cgq[tid] = cg[h * T_LEN + tq0 + tid];

  const int q = tid >> 2;          // 0..63
  const int p0 = (tid & 3) * 16;   // 0,16,32,48
  float yacc[16];
  {
    const float* yp = ybuf + (size_t)(tq0 + q) * INTER + h * HDIM + p0;
#pragma unroll
    for (int k = 0; k < 16; ++k) yacc[k] = yp[k];
  }

  for (int st = 0; st <= qt; ++st) {
    const int ts0 = st * 64;
    __syncthreads();   // previous iteration finished reading Bl/Vl/Sc
    for (int i = tid; i < 64 * 128; i += 256) {
      int r = i >> 7, c = i & 127;
      Bl[r][c] = Bbuf[(ts0 + r) * NSTATE + c];
    }
    for (int i = tid; i < 64 * 64; i += 256) {
      int r = i >> 6, c = i & 63;
      Vl[r][c] = vbuf[(size_t)(ts0 + r) * INTER + h * HDIM + c];
    }
    if (tid < 64) cgs[tid] = cg[h * T_LEN + ts0 + tid];
    __syncthreads();

    // scores: thread computes 16 scores for (q, s = (tid&3)+4j)
    {
      const int ssub = tid & 3;
      float sacc[16];
#pragma unroll
      for (int j = 0; j < 16; ++j) sacc[j] = 0.f;
      for (int k = 0; k < 128; ++k) {
        float cv = Cl[q][k];
#pragma unroll
        for (int j = 0; j < 16; ++j) sacc[j] += cv * Bl[ssub + 4 * j][k];
      }
      const int tg = tq0 + q;
      const float cq = cgq[q];
#pragma unroll
      for (int j = 0; j < 16; ++j) {
        int s = ssub + 4 * j;
        int sg = ts0 + s;
        float val = 0.f;
        if (sg <= tg) {
          int lvl = 31 - __clz((unsigned)(sg ^ (tg + 1)));
          val = sacc[j] * __expf(cq - cgs[s]) * Lsl[q][lvl];
        }
        Sc[q][s] = val;
      }
    }
    __syncthreads();

    // y accumulation: y[q][p0..p0+16) += sum_s Sc[q][s] * Vl[s][p]
    for (int s = 0; s < 64; ++s) {
      float sc = Sc[q][s];
#pragma unroll
      for (int k = 0; k < 16; ++k) yacc[k] += sc * Vl[s][p0 + k];
    }
  }

  float* yp = ybuf + (size_t)(tq0 + q) * INTER + h * HDIM + p0;
#pragma unroll
  for (int k = 0; k < 16; ++k) yp[k] = yacc[k];
}

// ---------------- gated RMSNorm (in-place on ybuf) ----------------
__global__ __launch_bounds__(256) void rmsnorm_gate(
    float* __restrict__ ybuf, const float* __restrict__ zx,
    const float* __restrict__ w) {
  __shared__ float red[4];
  const int t = blockIdx.x, tid = threadIdx.x;
  const float* zrow = zx + (size_t)t * PROJ;   // z = first INTER cols
  float* yrow = ybuf + (size_t)t * INTER;
  float yg[8];
  float ss = 0.f;
#pragma unroll
  for (int i = 0; i < 8; ++i) {
    int c = tid + 256 * i;
    float z = zrow[c];
    float g = yrow[c] * silu_f(z);
    yg[i] = g;
    ss += g * g;
  }
#pragma unroll
  for (int off = 32; off; off >>= 1) ss += __shfl_down(ss, off, 64);
  if ((tid & 63) == 0) red[tid >> 6] = ss;
  __syncthreads();
  if (tid == 0) red[0] = red[0] + red[1] + red[2] + red[3];
  __syncthreads();
  const float scale = rsqrtf(red[0] / (float)INTER + EPS);
#pragma unroll
  for (int i = 0; i < 8; ++i) {
    int c = tid + 256 * i;
    yrow[c] = yg[i] * scale * w[c];
  }
}

// ---------------- launch ----------------
extern "C" void kernel_launch(void* const* d_in, const int* in_sizes, int n_in,
                              void* d_out, int out_size, void* d_ws, size_t ws_size,
                              hipStream_t stream) {
  const float* hs        = (const float*)d_in[0];
  const float* in_proj_w = (const float*)d_in[1];
  const float* in_proj_b = (const float*)d_in[2];
  const float* conv_w    = (const float*)d_in[3];
  const float* dt_bias   = (const float*)d_in[4];
  const float* A_log     = (const float*)d_in[5];
  const float* L_param   = (const float*)d_in[6];
  const float* Dp        = (const float*)d_in[7];
  const float* rms_w     = (const float*)d_in[8];
  const float* out_proj_w= (const float*)d_in[9];
  const float* out_proj_b= (const float*)d_in[10];
  float* out = (float*)d_out;

  float* ws = (float*)d_ws;
  float* zx   = ws;                                  // T*PROJ
  float* vbuf = zx + (size_t)T_LEN * PROJ;           // T*INTER
  float* ybuf = vbuf + (size_t)T_LEN * INTER;        // T*INTER
  float* Bbuf = ybuf + (size_t)T_LEN * INTER;        // T*NSTATE
  float* Cbuf = Bbuf + (size_t)T_LEN * NSTATE;       // T*NSTATE
  float* gbuf = Cbuf + (size_t)T_LEN * NSTATE;       // T*NHEAD
  float* cgb  = gbuf + (size_t)T_LEN * NHEAD;        // NHEAD*T
  float* dtb  = cgb + (size_t)T_LEN * NHEAD;         // T*NHEAD
  float* Lsb  = dtb + (size_t)T_LEN * NHEAD;         // T*NHEAD*NLVL

  // 1. in_proj: zx = hs @ W^T + b   (M=1024, N=4864, K=1024)
  gemm_nt<<<dim3(PROJ / 64, T_LEN / 64), 256, 0, stream>>>(
      hs, in_proj_w, in_proj_b, zx, T_LEN, PROJ, HID);

  // 2. pointwise: dt, g, level scales
  pointwise_dt<<<T_LEN, 512, 0, stream>>>(zx, dt_bias, A_log, L_param, dtb, gbuf, Lsb);

  // 3. conv + silu + split (v, D-residual into ybuf, B, C)
  conv_silu<<<(T_LEN * CONV_DIM + 255) / 256, 256, 0, stream>>>(
      zx, conv_w, dtb, Dp, vbuf, ybuf, Bbuf, Cbuf);

  // 4. per-head cumsum
  scan_g<<<NHEAD, T_LEN, 0, stream>>>(gbuf, cgb);

  // 5. attention-like quadratic part (accumulates onto D-residual in ybuf)
  attn_kernel<<<dim3(T_LEN / 64, NHEAD), 256, 0, stream>>>(
      Bbuf, Cbuf, vbuf, cgb, Lsb, ybuf);

  // 6. gated RMSNorm (in place)
  rmsnorm_gate<<<T_LEN, 256, 0, stream>>>(ybuf, zx, rms_w);

  // 7. out_proj: out = y @ W2^T + b2  (M=1024, N=1024, K=2048)
  gemm_nt<<<dim3(HID / 64, T_LEN / 64), 256, 0, stream>>>(
      ybuf, out_proj_w, out_proj_b, out, T_LEN, HID, INTER);
}

// Round 3
// 267.460 us; speedup vs baseline: 5.3283x; 5.3283x over previous
//
#include <hip/hip_runtime.h>
#include <hip/hip_bf16.h>
#include <math.h>

// ---------------- model constants ----------------
#define T_LEN 1024
#define HID 1024
#define NHEAD 32
#define HDIM 64         // P
#define NSTATE 128      // N
#define NLVL 15
#define KCONV 4
#define INTER 2048
#define CONV_DIM 2304   // INTER + 2*N
#define PROJ 4864       // INTER + CONV_DIM + H*(NL+1)
#define EPS 1e-5f

typedef __attribute__((ext_vector_type(8))) _Float16 half8;
typedef __attribute__((ext_vector_type(4))) float float4v;
typedef unsigned short ushort_t;

__device__ __forceinline__ float softplus_f(float x) {
  return fmaxf(x, 0.f) + log1pf(expf(-fabsf(x)));
}
__device__ __forceinline__ float silu_f(float x) {
  return x / (1.f + expf(-x));
}
__device__ __forceinline__ ushort_t f2h(float f) {
  union { _Float16 h; ushort_t u; } v;
  v.h = (_Float16)f;   // v_cvt_f16_f32, RNE
  return v.u;
}

// ---------------- f32 -> f16 bulk convert ----------------
__global__ __launch_bounds__(256) void f32_to_f16(const float* __restrict__ src,
                                                  ushort_t* __restrict__ dst, int n4) {
  int i = blockIdx.x * 256 + threadIdx.x;
  if (i >= n4) return;
  float4 v = reinterpret_cast<const float4*>(src)[i];
  union { ushort_t u[4]; unsigned long long ll; } o;
  o.u[0] = f2h(v.x); o.u[1] = f2h(v.y); o.u[2] = f2h(v.z); o.u[3] = f2h(v.w);
  reinterpret_cast<unsigned long long*>(dst)[i] = o.ll;
}

// ---------------- f16 MFMA GEMM: C[m,n] = A[m,:].B[n,:] + bias[n] ----------------
// A:(M,K) f16 row-major, B:(N,K) f16 row-major, C:(M,N) f32. Tile 128x128, BK=32.
__global__ __launch_bounds__(256) void gemm_f16(
    const ushort_t* __restrict__ A, const ushort_t* __restrict__ B,
    const float* __restrict__ bias, float* __restrict__ C,
    int M, int N, int K) {
  __shared__ ushort_t As[128][40];   // row stride 80B = 5*16B -> <=2-way on b128
  __shared__ ushort_t Bs[128][40];
  const int tid = threadIdx.x;
  const int w = tid >> 6, L = tid & 63;
  const int m0 = blockIdx.y * 128, n0 = blockIdx.x * 128;
  const int mq = (w & 1) * 64, nq = (w >> 1) * 64;
  float4v acc[4][4];
#pragma unroll
  for (int i = 0; i < 4; ++i)
#pragma unroll
    for (int j = 0; j < 4; ++j) acc[i][j] = (float4v){0.f, 0.f, 0.f, 0.f};

  for (int kk = 0; kk < K; kk += 32) {
    __syncthreads();
#pragma unroll
    for (int i = 0; i < 2; ++i) {
      int u = tid + 256 * i;
      int row = u >> 2, kb = (u & 3) * 8;
      *reinterpret_cast<half8*>(&As[row][kb]) =
          *reinterpret_cast<const half8*>(A + (size_t)(m0 + row) * K + kk + kb);
      *reinterpret_cast<half8*>(&Bs[row][kb]) =
          *reinterpret_cast<const half8*>(B + (size_t)(n0 + row) * K + kk + kb);
    }
    __syncthreads();
    half8 af[4], bf[4];
#pragma unroll
    for (int t = 0; t < 4; ++t) {
      af[t] = *reinterpret_cast<const half8*>(&As[mq + t * 16 + (L & 15)][(L >> 4) * 8]);
      bf[t] = *reinterpret_cast<const half8*>(&Bs[nq + t * 16 + (L & 15)][(L >> 4) * 8]);
    }
#pragma unroll
    for (int mt = 0; mt < 4; ++mt)
#pragma unroll
      for (int nt = 0; nt < 4; ++nt)
        acc[mt][nt] = __builtin_amdgcn_mfma_f32_16x16x32_f16(af[mt], bf[nt], acc[mt][nt], 0, 0, 0);
  }
  const int qrow = (L >> 4) * 4;
#pragma unroll
  for (int mt = 0; mt < 4; ++mt) {
#pragma unroll
    for (int nt = 0; nt < 4; ++nt) {
      int col = n0 + nq + nt * 16 + (L & 15);
      float bv = bias[col];
#pragma unroll
      for (int r = 0; r < 4; ++r) {
        int row = m0 + mq + mt * 16 + qrow + r;
        C[(size_t)row * N + col] = acc[mt][nt][r] + bv;
      }
    }
  }
}

// ---------------- per-token pointwise: dt, g, level scales ----------------
__global__ __launch_bounds__(512) void pointwise_dt(
    const float* __restrict__ zx, const float* __restrict__ dt_bias,
    const float* __restrict__ A_log, const float* __restrict__ L_param,
    float* __restrict__ dtbuf, float* __restrict__ gbuf,
    float* __restrict__ Lsbuf) {
  const int t = blockIdx.x;
  const int j = threadIdx.x;   // 512 = 480 + 32
  const float* row = zx + (size_t)t * PROJ;
  if (j < NHEAD * NLVL) {
    float x = L_param[j] * row[INTER + CONV_DIM + NHEAD + j];
    Lsbuf[(size_t)t * (NHEAD * NLVL) + j] = softplus_f(x);
  } else {
    int h = j - NHEAD * NLVL;
    float x = row[INTER + CONV_DIM + h] + dt_bias[h];
    float dt = softplus_f(x);
    dtbuf[t * NHEAD + h] = dt;
    gbuf[t * NHEAD + h] = -expf(A_log[h]) * dt;
  }
}

// ---------------- depthwise causal conv (K=4) + SiLU + split ----------------
__global__ __launch_bounds__(256) void conv_silu(
    const float* __restrict__ zx, const float* __restrict__ conv_w,
    const float* __restrict__ dtbuf, const float* __restrict__ Dp,
    ushort_t* __restrict__ vb, float* __restrict__ ybuf,
    ushort_t* __restrict__ Bb, ushort_t* __restrict__ Cb) {
  int idx = blockIdx.x * 256 + threadIdx.x;
  if (idx >= T_LEN * CONV_DIM) return;
  int t = idx / CONV_DIM;
  int c = idx - t * CONV_DIM;
  float acc = 0.f;
#pragma unroll
  for (int w = 0; w < KCONV; ++w) {
    int tt = t - (KCONV - 1) + w;
    if (tt >= 0) acc += zx[(size_t)tt * PROJ + INTER + c] * conv_w[c * KCONV + w];
  }
  float sil = silu_f(acc);
  if (c < INTER) {
    int h = c >> 6;
    float dt = dtbuf[t * NHEAD + h];
    vb[(size_t)t * INTER + c] = f2h(sil * dt);    // v = x*dt (f16)
    ybuf[(size_t)t * INTER + c] = sil * Dp[h];    // D residual (f32)
  } else if (c < INTER + NSTATE) {
    Bb[t * NSTATE + (c - INTER)] = f2h(sil);
  } else {
    Cb[t * NSTATE + (c - INTER - NSTATE)] = f2h(sil);
  }
}

// ---------------- per-head inclusive cumsum of g (fp64) ----------------
__global__ __launch_bounds__(1024) void scan_g(const float* __restrict__ gbuf,
                                               double* __restrict__ cgd) {
  __shared__ double buf[T_LEN];
  const int h = blockIdx.x, t = threadIdx.x;
  buf[t] = (double)gbuf[t * NHEAD + h];
  __syncthreads();
  for (int off = 1; off < T_LEN; off <<= 1) {
    double v = buf[t];
    double a = (t >= off) ? buf[t - off] : 0.0;
    __syncthreads();
    buf[t] = v + a;
    __syncthreads();
  }
  cgd[(size_t)h * T_LEN + t] = buf[t];
}

// ---------------- MFMA attention ----------------
// block = (head h, q-tile of 64); 256 threads = 4 waves; wave w owns q rows w*16..w*16+15
__global__ __launch_bounds__(256) void attn_mfma(
    const ushort_t* __restrict__ Bb, const ushort_t* __restrict__ Cb,
    const ushort_t* __restrict__ vb, const double* __restrict__ cgd,
    const float* __restrict__ Lsb, float* __restrict__ ybuf) {
  __shared__ ushort_t Bl[64][136];   // 272B stride = 17*16B -> 2-way (free)
  __shared__ ushort_t Sl[64][72];    // 144B stride = 9*16B
  __shared__ ushort_t Vt[64][72];    // V transposed [p][s]
  __shared__ float Lsl[64][16];
  __shared__ float cgq[64];
  __shared__ float cgs[64];

  const int qt = blockIdx.x, h = blockIdx.y;
  const int tid = threadIdx.x;
  const int w = tid >> 6, L = tid & 63;
  const int tq0 = qt * 64;
  const double* cgh = cgd + (size_t)h * T_LEN;
  const double base = cgh[tq0];

  for (int i = tid; i < 64 * NLVL; i += 256) {
    int r = i / NLVL, l = i - r * NLVL;
    Lsl[r][l] = Lsb[(size_t)(tq0 + r) * (NHEAD * NLVL) + h * NLVL + l];
  }
  if (tid < 64) cgq[tid] = (float)(cgh[tq0 + tid] - base);

  // C fragments in registers (rows w*16 + (L&15), K=128 -> 4 frags)
  half8 cfrag[4];
  {
    const ushort_t* cr = Cb + (size_t)(tq0 + w * 16 + (L & 15)) * NSTATE + (L >> 4) * 8;
#pragma unroll
    for (int ks = 0; ks < 4; ++ks)
      cfrag[ks] = *reinterpret_cast<const half8*>(cr + ks * 32);
  }
  float4v yac[4];
#pragma unroll
  for (int i = 0; i < 4; ++i) yac[i] = (float4v){0.f, 0.f, 0.f, 0.f};

  const int qrow = w * 16 + ((L >> 4) << 2);   // + r gives the C/D row

  for (int st = 0; st <= qt; ++st) {
    const int ts0 = st * 64;
    __syncthreads();   // previous iteration done reading Bl/Vt
    // stage B tile (64 x 128 f16)
#pragma unroll
    for (int i = 0; i < 4; ++i) {
      int u = tid + 256 * i;
      int row = u >> 4, kb = (u & 15) * 8;
      *reinterpret_cast<half8*>(&Bl[row][kb]) =
          *reinterpret_cast<const half8*>(Bb + (size_t)(ts0 + row) * NSTATE + kb);
    }
    // stage V transposed: Vt[p][s] = v[ts0+s][h*64+p]
    for (int i = tid; i < 2048; i += 256) {
      int s = i >> 5, p2 = (i & 31) * 2;
      unsigned pv = *reinterpret_cast<const unsigned*>(vb + (size_t)(ts0 + s) * INTER + h * HDIM + p2);
      Vt[p2][s] = (ushort_t)(pv & 0xFFFF);
      Vt[p2 + 1][s] = (ushort_t)(pv >> 16);
    }
    if (tid < 64) cgs[tid] = (float)(cgh[ts0 + tid] - base);
    __syncthreads();

    // scores S = C . B^T  (wave w: q rows w*16..+15, all 64 s)
    float4v sac[4];
#pragma unroll
    for (int nt = 0; nt < 4; ++nt) sac[nt] = (float4v){0.f, 0.f, 0.f, 0.f};
#pragma unroll
    for (int ks = 0; ks < 4; ++ks) {
#pragma unroll
      for (int nt = 0; nt < 4; ++nt) {
        half8 bfrag = *reinterpret_cast<const half8*>(&Bl[nt * 16 + (L & 15)][ks * 32 + (L >> 4) * 8]);
        sac[nt] = __builtin_amdgcn_mfma_f32_16x16x32_f16(cfrag[ks], bfrag, sac[nt], 0, 0, 0);
      }
    }
    // modulate (decay * level scale * mask) and write to Sl in A-operand feed layout
#pragma unroll
    for (int nt = 0; nt < 4; ++nt) {
      int s = nt * 16 + (L & 15);
      int sg = ts0 + s;
      float cs = cgs[s];
#pragma unroll
      for (int r = 0; r < 4; ++r) {
        int q = qrow + r;
        int tg = tq0 + q;
        float val = 0.f;
        if (sg <= tg) {
          int lvl = 31 - __clz((unsigned)(sg ^ (tg + 1)));
          val = sac[nt][r] * __expf(cgq[q] - cs) * Lsl[q][lvl];
        }
        Sl[q][s] = f2h(val);
      }
    }
    // Sl rows w*16..+15 written and read by the same wave -> wait own ds_writes
    __builtin_amdgcn_s_waitcnt(0);
    // PV: Y += S . V   (A = Sl rows, B = Vt rows = p)
#pragma unroll
    for (int ks = 0; ks < 2; ++ks) {
      half8 af = *reinterpret_cast<const half8*>(&Sl[w * 16 + (L & 15)][ks * 32 + (L >> 4) * 8]);
#pragma unroll
      for (int pt = 0; pt < 4; ++pt) {
        half8 bfv = *reinterpret_cast<const half8*>(&Vt[pt * 16 + (L & 15)][ks * 32 + (L >> 4) * 8]);
        yac[pt] = __builtin_amdgcn_mfma_f32_16x16x32_f16(af, bfv, yac[pt], 0, 0, 0);
      }
    }
  }
  // epilogue: accumulate onto D-residual already in ybuf
#pragma unroll
  for (int pt = 0; pt < 4; ++pt) {
    int p = pt * 16 + (L & 15);
#pragma unroll
    for (int r = 0; r < 4; ++r) {
      int q = qrow + r;
      float* yp = ybuf + (size_t)(tq0 + q) * INTER + h * HDIM + p;
      *yp += yac[pt][r];
    }
  }
}

// ---------------- gated RMSNorm -> f16 ----------------
__global__ __launch_bounds__(256) void rmsnorm_gate(
    const float* __restrict__ ybuf, const float* __restrict__ zx,
    const float* __restrict__ w, ushort_t* __restrict__ yhf) {
  __shared__ float red[4];
  const int t = blockIdx.x, tid = threadIdx.x;
  const float* zrow = zx + (size_t)t * PROJ;
  const float* yrow = ybuf + (size_t)t * INTER;
  float yg[8];
  float ss = 0.f;
#pragma unroll
  for (int i = 0; i < 8; ++i) {
    int c = tid + 256 * i;
    float g = yrow[c] * silu_f(zrow[c]);
    yg[i] = g;
    ss += g * g;
  }
#pragma unroll
  for (int off = 32; off; off >>= 1) ss += __shfl_down(ss, off, 64);
  if ((tid & 63) == 0) red[tid >> 6] = ss;
  __syncthreads();
  if (tid == 0) red[0] = red[0] + red[1] + red[2] + red[3];
  __syncthreads();
  const float scale = rsqrtf(red[0] / (float)INTER + EPS);
#pragma unroll
  for (int i = 0; i < 8; ++i) {
    int c = tid + 256 * i;
    yhf[(size_t)t * INTER + c] = f2h(yg[i] * scale * w[c]);
  }
}

// ---------------- launch ----------------
extern "C" void kernel_launch(void* const* d_in, const int* in_sizes, int n_in,
                              void* d_out, int out_size, void* d_ws, size_t ws_size,
                              hipStream_t stream) {
  const float* hs        = (const float*)d_in[0];
  const float* in_proj_w = (const float*)d_in[1];
  const float* in_proj_b = (const float*)d_in[2];
  const float* conv_w    = (const float*)d_in[3];
  const float* dt_bias   = (const float*)d_in[4];
  const float* A_log     = (const float*)d_in[5];
  const float* L_param   = (const float*)d_in[6];
  const float* Dp        = (const float*)d_in[7];
  const float* rms_w     = (const float*)d_in[8];
  const float* out_proj_w= (const float*)d_in[9];
  const float* out_proj_b= (const float*)d_in[10];
  float* out = (float*)d_out;

  char* W = (char*)d_ws;
  size_t off = 0;
  auto alloc = [&](size_t bytes) { void* p = W + off; off = (off + bytes + 255) & ~(size_t)255; return p; };
  double*   cgd = (double*)  alloc((size_t)NHEAD * T_LEN * 8);
  float*    zx  = (float*)   alloc((size_t)T_LEN * PROJ * 4);
  float*    ybuf= (float*)   alloc((size_t)T_LEN * INTER * 4);
  float*    gbuf= (float*)   alloc((size_t)T_LEN * NHEAD * 4);
  float*    dtb = (float*)   alloc((size_t)T_LEN * NHEAD * 4);
  float*    Lsb = (float*)   alloc((size_t)T_LEN * NHEAD * NLVL * 4);
  ushort_t* hsb = (ushort_t*)alloc((size_t)T_LEN * HID * 2);
  ushort_t* Wib = (ushort_t*)alloc((size_t)PROJ * HID * 2);
  ushort_t* Wob = (ushort_t*)alloc((size_t)HID * INTER * 2);
  ushort_t* yhf = (ushort_t*)alloc((size_t)T_LEN * INTER * 2);
  ushort_t* vb  = (ushort_t*)alloc((size_t)T_LEN * INTER * 2);
  ushort_t* Bb  = (ushort_t*)alloc((size_t)T_LEN * NSTATE * 2);
  ushort_t* Cb  = (ushort_t*)alloc((size_t)T_LEN * NSTATE * 2);

  // 0. f16 conversions
  f32_to_f16<<<(T_LEN * HID / 4 + 255) / 256, 256, 0, stream>>>(hs, hsb, T_LEN * HID / 4);
  f32_to_f16<<<(PROJ * HID / 4 + 255) / 256, 256, 0, stream>>>(in_proj_w, Wib, PROJ * HID / 4);
  f32_to_f16<<<(HID * INTER / 4 + 255) / 256, 256, 0, stream>>>(out_proj_w, Wob, HID * INTER / 4);

  // 1. in_proj: zx = hs @ W^T + b   (M=1024, N=4864, K=1024)
  gemm_f16<<<dim3(PROJ / 128, T_LEN / 128), 256, 0, stream>>>(
      hsb, Wib, in_proj_b, zx, T_LEN, PROJ, HID);

  // 2. pointwise
  pointwise_dt<<<T_LEN, 512, 0, stream>>>(zx, dt_bias, A_log, L_param, dtb, gbuf, Lsb);

  // 3. conv + silu + split
  conv_silu<<<(T_LEN * CONV_DIM + 255) / 256, 256, 0, stream>>>(
      zx, conv_w, dtb, Dp, vb, ybuf, Bb, Cb);

  // 4. fp64 cumsum
  scan_g<<<NHEAD, T_LEN, 0, stream>>>(gbuf, cgd);

  // 5. MFMA attention
  attn_mfma<<<dim3(T_LEN / 64, NHEAD), 256, 0, stream>>>(Bb, Cb, vb, cgd, Lsb, ybuf);

  // 6. gated RMSNorm -> f16
  rmsnorm_gate<<<T_LEN, 256, 0, stream>>>(ybuf, zx, rms_w, yhf);

  // 7. out_proj: out = y @ W2^T + b2  (M=1024, N=1024, K=2048)
  gemm_f16<<<dim3(HID / 128, T_LEN / 128), 256, 0, stream>>>(
      yhf, Wob, out_proj_b, out, T_LEN, HID, INTER);
}

// Round 4
// 240.708 us; speedup vs baseline: 5.9205x; 1.1111x over previous
//
#include <hip/hip_runtime.h>
#include <hip/hip_bf16.h>
#include <math.h>

// ---------------- model constants ----------------
#define T_LEN 1024
#define HID 1024
#define NHEAD 32
#define HDIM 64         // P
#define NSTATE 128      // N
#define NLVL 15
#define KCONV 4
#define INTER 2048
#define CONV_DIM 2304   // INTER + 2*N
#define PROJ 4864       // INTER + CONV_DIM + H*(NL+1)
#define EPS 1e-5f

typedef __attribute__((ext_vector_type(8))) _Float16 half8;
typedef __attribute__((ext_vector_type(4))) float float4v;
typedef unsigned short ushort_t;

__device__ __forceinline__ float softplus_f(float x) {
  return fmaxf(x, 0.f) + log1pf(expf(-fabsf(x)));
}
__device__ __forceinline__ float silu_f(float x) {
  return x / (1.f + expf(-x));
}
__device__ __forceinline__ ushort_t f2h(float f) {
  union { _Float16 h; ushort_t u; } v;
  v.h = (_Float16)f;   // v_cvt_f16_f32, RNE
  return v.u;
}

// ---------------- f32 -> f16 bulk convert ----------------
__global__ __launch_bounds__(256) void f32_to_f16(const float* __restrict__ src,
                                                  ushort_t* __restrict__ dst, int n4) {
  int i = blockIdx.x * 256 + threadIdx.x;
  if (i >= n4) return;
  float4 v = reinterpret_cast<const float4*>(src)[i];
  union { ushort_t u[4]; unsigned long long ll; } o;
  o.u[0] = f2h(v.x); o.u[1] = f2h(v.y); o.u[2] = f2h(v.z); o.u[3] = f2h(v.w);
  reinterpret_cast<unsigned long long*>(dst)[i] = o.ll;
}

// ---------------- f16 MFMA GEMM: C[m,n] = A[m,:].B[n,:] + bias[n] ----------------
__global__ __launch_bounds__(256) void gemm_f16(
    const ushort_t* __restrict__ A, const ushort_t* __restrict__ B,
    const float* __restrict__ bias, float* __restrict__ C,
    int M, int N, int K) {
  __shared__ ushort_t As[128][40];   // row stride 80B -> <=2-way on b128
  __shared__ ushort_t Bs[128][40];
  const int tid = threadIdx.x;
  const int w = tid >> 6, L = tid & 63;
  const int m0 = blockIdx.y * 128, n0 = blockIdx.x * 128;
  const int mq = (w & 1) * 64, nq = (w >> 1) * 64;
  float4v acc[4][4];
#pragma unroll
  for (int i = 0; i < 4; ++i)
#pragma unroll
    for (int j = 0; j < 4; ++j) acc[i][j] = (float4v){0.f, 0.f, 0.f, 0.f};

  for (int kk = 0; kk < K; kk += 32) {
    __syncthreads();
#pragma unroll
    for (int i = 0; i < 2; ++i) {
      int u = tid + 256 * i;
      int row = u >> 2, kb = (u & 3) * 8;
      *reinterpret_cast<half8*>(&As[row][kb]) =
          *reinterpret_cast<const half8*>(A + (size_t)(m0 + row) * K + kk + kb);
      *reinterpret_cast<half8*>(&Bs[row][kb]) =
          *reinterpret_cast<const half8*>(B + (size_t)(n0 + row) * K + kk + kb);
    }
    __syncthreads();
    half8 af[4], bf[4];
#pragma unroll
    for (int t = 0; t < 4; ++t) {
      af[t] = *reinterpret_cast<const half8*>(&As[mq + t * 16 + (L & 15)][(L >> 4) * 8]);
      bf[t] = *reinterpret_cast<const half8*>(&Bs[nq + t * 16 + (L & 15)][(L >> 4) * 8]);
    }
#pragma unroll
    for (int mt = 0; mt < 4; ++mt)
#pragma unroll
      for (int nt = 0; nt < 4; ++nt)
        acc[mt][nt] = __builtin_amdgcn_mfma_f32_16x16x32_f16(af[mt], bf[nt], acc[mt][nt], 0, 0, 0);
  }
  const int qrow = (L >> 4) * 4;
#pragma unroll
  for (int mt = 0; mt < 4; ++mt) {
#pragma unroll
    for (int nt = 0; nt < 4; ++nt) {
      int col = n0 + nq + nt * 16 + (L & 15);
      float bv = bias[col];
#pragma unroll
      for (int r = 0; r < 4; ++r) {
        int row = m0 + mq + mt * 16 + qrow + r;
        C[(size_t)row * N + col] = acc[mt][nt][r] + bv;
      }
    }
  }
}

// ---------------- per-token pointwise: dt, g, level scales ----------------
__global__ __launch_bounds__(512) void pointwise_dt(
    const float* __restrict__ zx, const float* __restrict__ dt_bias,
    const float* __restrict__ A_log, const float* __restrict__ L_param,
    float* __restrict__ dtbuf, float* __restrict__ gbuf,
    float* __restrict__ Lsbuf) {
  const int t = blockIdx.x;
  const int j = threadIdx.x;
  const float* row = zx + (size_t)t * PROJ;
  if (j < NHEAD * NLVL) {
    float x = L_param[j] * row[INTER + CONV_DIM + NHEAD + j];
    Lsbuf[(size_t)t * (NHEAD * NLVL) + j] = softplus_f(x);
  } else {
    int h = j - NHEAD * NLVL;
    float x = row[INTER + CONV_DIM + h] + dt_bias[h];
    float dt = softplus_f(x);
    dtbuf[t * NHEAD + h] = dt;
    gbuf[t * NHEAD + h] = -expf(A_log[h]) * dt;
  }
}

// ---------------- depthwise causal conv (K=4) + SiLU + split ----------------
__global__ __launch_bounds__(256) void conv_silu(
    const float* __restrict__ zx, const float* __restrict__ conv_w,
    const float* __restrict__ dtbuf, const float* __restrict__ Dp,
    ushort_t* __restrict__ vb, float* __restrict__ ybuf,
    ushort_t* __restrict__ Bb, ushort_t* __restrict__ Cb) {
  int idx = blockIdx.x * 256 + threadIdx.x;
  if (idx >= T_LEN * CONV_DIM) return;
  int t = idx / CONV_DIM;
  int c = idx - t * CONV_DIM;
  float acc = 0.f;
#pragma unroll
  for (int w = 0; w < KCONV; ++w) {
    int tt = t - (KCONV - 1) + w;
    if (tt >= 0) acc += zx[(size_t)tt * PROJ + INTER + c] * conv_w[c * KCONV + w];
  }
  float sil = silu_f(acc);
  if (c < INTER) {
    int h = c >> 6;
    float dt = dtbuf[t * NHEAD + h];
    vb[(size_t)t * INTER + c] = f2h(sil * dt);    // v = x*dt (f16)
    ybuf[(size_t)t * INTER + c] = sil * Dp[h];    // D residual (f32)
  } else if (c < INTER + NSTATE) {
    Bb[t * NSTATE + (c - INTER)] = f2h(sil);
  } else {
    Cb[t * NSTATE + (c - INTER - NSTATE)] = f2h(sil);
  }
}

// ---------------- transpose v: vt[h*64+p][t] = vb[t][h*64+p] ----------------
__global__ __launch_bounds__(256) void vtrans(const ushort_t* __restrict__ vb,
                                              ushort_t* __restrict__ vt) {
  __shared__ ushort_t Tl[64][72];
  const int tid = threadIdx.x;
  const int t0 = blockIdx.x * 64, c0 = blockIdx.y * 64;
#pragma unroll
  for (int i = 0; i < 2; ++i) {
    int u = tid + 256 * i;
    int r = u >> 3, c8 = (u & 7) * 8;
    *reinterpret_cast<half8*>(&Tl[r][c8]) =
        *reinterpret_cast<const half8*>(vb + (size_t)(t0 + r) * INTER + c0 + c8);
  }
  __syncthreads();
#pragma unroll
  for (int i = 0; i < 2; ++i) {
    int u = tid + 256 * i;
    int p = u >> 3, t8 = (u & 7) * 8;
    union { ushort_t u16[8]; half8 h; } o;
#pragma unroll
    for (int j = 0; j < 8; ++j) o.u16[j] = Tl[t8 + j][p];
    *reinterpret_cast<half8*>(vt + (size_t)(c0 + p) * T_LEN + t0 + t8) = o.h;
  }
}

// ---------------- per-head inclusive cumsum of g (fp64) ----------------
__global__ __launch_bounds__(1024) void scan_g(const float* __restrict__ gbuf,
                                               double* __restrict__ cgd) {
  __shared__ double buf[T_LEN];
  const int h = blockIdx.x, t = threadIdx.x;
  buf[t] = (double)gbuf[t * NHEAD + h];
  __syncthreads();
  for (int off = 1; off < T_LEN; off <<= 1) {
    double v = buf[t];
    double a = (t >= off) ? buf[t - off] : 0.0;
    __syncthreads();
    buf[t] = v + a;
    __syncthreads();
  }
  cgd[(size_t)h * T_LEN + t] = buf[t];
}

// ---------------- split-K MFMA attention ----------------
// Work item (per block): (head h, q-tile qt of 64 rows, s-chunk j of <=4 s-tiles).
// Items per head: qt 0-3 ->1 chunk, 4-7 ->2, 8-11 ->3, 12-15 ->4  => 40.
// Partial Y accumulated via atomicAdd onto D-residual-seeded ybuf.
__global__ __launch_bounds__(256) void attn_mfma(
    const ushort_t* __restrict__ Bb, const ushort_t* __restrict__ Cb,
    const ushort_t* __restrict__ vt, const double* __restrict__ cgd,
    const float* __restrict__ Lsb, float* __restrict__ ybuf) {
  __shared__ ushort_t Bl[64][136];   // 272B stride -> 2-way (free)
  __shared__ ushort_t Vtl[64][72];   // [p][s], staged from pre-transposed vt
  __shared__ ushort_t Sl[64][72];
  __shared__ float Lsl[64][17];
  __shared__ float cgq[64];
  __shared__ float cgs[64];

  const int item = blockIdx.x;
  const int h = item / 40;
  const int rem = item - h * 40;
  int qt, j;
  if (rem < 4)        { qt = rem;                 j = 0; }
  else if (rem < 12)  { qt = 4 + (rem - 4) / 2;   j = (rem - 4) % 2; }
  else if (rem < 24)  { qt = 8 + (rem - 12) / 3;  j = (rem - 12) % 3; }
  else                { qt = 12 + (rem - 24) / 4; j = (rem - 24) % 4; }

  const int tid = threadIdx.x;
  const int w = tid >> 6, L = tid & 63;
  const int tq0 = qt * 64;
  const double* cgh = cgd + (size_t)h * T_LEN;
  const double base = cgh[tq0];

  for (int i = tid; i < 64 * NLVL; i += 256) {
    int r = i / NLVL, l = i - r * NLVL;
    Lsl[r][l] = Lsb[(size_t)(tq0 + r) * (NHEAD * NLVL) + h * NLVL + l];
  }
  if (tid < 64) cgq[tid] = (float)(cgh[tq0 + tid] - base);

  // C fragments in registers (rows w*16 + (L&15), K=128 -> 4 frags)
  half8 cfrag[4];
  {
    const ushort_t* cr = Cb + (size_t)(tq0 + w * 16 + (L & 15)) * NSTATE + (L >> 4) * 8;
#pragma unroll
    for (int ks = 0; ks < 4; ++ks)
      cfrag[ks] = *reinterpret_cast<const half8*>(cr + ks * 32);
  }
  float4v yac[4];
#pragma unroll
  for (int i = 0; i < 4; ++i) yac[i] = (float4v){0.f, 0.f, 0.f, 0.f};

  const int qrow = w * 16 + ((L >> 4) << 2);

  const int st0 = 4 * j;
  const int st1 = min(4 * j + 4, qt + 1);
  for (int st = st0; st < st1; ++st) {
    const int ts0 = st * 64;
    __syncthreads();   // prev iter done reading; initial staging visible
    // stage B tile (64 x 128 f16)
#pragma unroll
    for (int i = 0; i < 4; ++i) {
      int u = tid + 256 * i;
      int row = u >> 4, kb = (u & 15) * 8;
      *reinterpret_cast<half8*>(&Bl[row][kb]) =
          *reinterpret_cast<const half8*>(Bb + (size_t)(ts0 + row) * NSTATE + kb);
    }
    // stage V^T tile (64 p x 64 s) — vectorized from pre-transposed vt
#pragma unroll
    for (int i = 0; i < 2; ++i) {
      int u = tid + 256 * i;
      int p = u >> 3, sc = (u & 7) * 8;
      *reinterpret_cast<half8*>(&Vtl[p][sc]) =
          *reinterpret_cast<const half8*>(vt + (size_t)(h * HDIM + p) * T_LEN + ts0 + sc);
    }
    if (tid < 64) cgs[tid] = (float)(cgh[ts0 + tid] - base);
    __syncthreads();

    // scores S = C . B^T
    float4v sac[4];
#pragma unroll
    for (int nt = 0; nt < 4; ++nt) sac[nt] = (float4v){0.f, 0.f, 0.f, 0.f};
#pragma unroll
    for (int ks = 0; ks < 4; ++ks) {
#pragma unroll
      for (int nt = 0; nt < 4; ++nt) {
        half8 bfrag = *reinterpret_cast<const half8*>(&Bl[nt * 16 + (L & 15)][ks * 32 + (L >> 4) * 8]);
        sac[nt] = __builtin_amdgcn_mfma_f32_16x16x32_f16(cfrag[ks], bfrag, sac[nt], 0, 0, 0);
      }
    }
    // modulate (decay * level scale * mask) -> Sl (f16)
#pragma unroll
    for (int nt = 0; nt < 4; ++nt) {
      int s = nt * 16 + (L & 15);
      int sg = ts0 + s;
      float cs = cgs[s];
#pragma unroll
      for (int r = 0; r < 4; ++r) {
        int q = qrow + r;
        int tg = tq0 + q;
        float val = 0.f;
        if (sg <= tg) {
          int lvl = 31 - __clz((unsigned)(sg ^ (tg + 1)));
          val = sac[nt][r] * __expf(cgq[q] - cs) * Lsl[q][lvl];
        }
        Sl[q][s] = f2h(val);
      }
    }
    __builtin_amdgcn_s_waitcnt(0);   // own ds_writes (wave-private rows)
    // PV: Y += S . V
#pragma unroll
    for (int ks = 0; ks < 2; ++ks) {
      half8 af = *reinterpret_cast<const half8*>(&Sl[w * 16 + (L & 15)][ks * 32 + (L >> 4) * 8]);
#pragma unroll
      for (int pt = 0; pt < 4; ++pt) {
        half8 bfv = *reinterpret_cast<const half8*>(&Vtl[pt * 16 + (L & 15)][ks * 32 + (L >> 4) * 8]);
        yac[pt] = __builtin_amdgcn_mfma_f32_16x16x32_f16(af, bfv, yac[pt], 0, 0, 0);
      }
    }
  }
  // epilogue: accumulate partial Y onto ybuf
#pragma unroll
  for (int pt = 0; pt < 4; ++pt) {
    int p = pt * 16 + (L & 15);
#pragma unroll
    for (int r = 0; r < 4; ++r) {
      int q = qrow + r;
      atomicAdd(ybuf + (size_t)(tq0 + q) * INTER + h * HDIM + p, yac[pt][r]);
    }
  }
}

// ---------------- gated RMSNorm -> f16 ----------------
__global__ __launch_bounds__(256) void rmsnorm_gate(
    const float* __restrict__ ybuf, const float* __restrict__ zx,
    const float* __restrict__ w, ushort_t* __restrict__ yhf) {
  __shared__ float red[4];
  const int t = blockIdx.x, tid = threadIdx.x;
  const float* zrow = zx + (size_t)t * PROJ;
  const float* yrow = ybuf + (size_t)t * INTER;
  float yg[8];
  float ss = 0.f;
#pragma unroll
  for (int i = 0; i < 8; ++i) {
    int c = tid + 256 * i;
    float g = yrow[c] * silu_f(zrow[c]);
    yg[i] = g;
    ss += g * g;
  }
#pragma unroll
  for (int off = 32; off; off >>= 1) ss += __shfl_down(ss, off, 64);
  if ((tid & 63) == 0) red[tid >> 6] = ss;
  __syncthreads();
  if (tid == 0) red[0] = red[0] + red[1] + red[2] + red[3];
  __syncthreads();
  const float scale = rsqrtf(red[0] / (float)INTER + EPS);
#pragma unroll
  for (int i = 0; i < 8; ++i) {
    int c = tid + 256 * i;
    yhf[(size_t)t * INTER + c] = f2h(yg[i] * scale * w[c]);
  }
}

// ---------------- launch ----------------
extern "C" void kernel_launch(void* const* d_in, const int* in_sizes, int n_in,
                              void* d_out, int out_size, void* d_ws, size_t ws_size,
                              hipStream_t stream) {
  const float* hs        = (const float*)d_in[0];
  const float* in_proj_w = (const float*)d_in[1];
  const float* in_proj_b = (const float*)d_in[2];
  const float* conv_w    = (const float*)d_in[3];
  const float* dt_bias   = (const float*)d_in[4];
  const float* A_log     = (const float*)d_in[5];
  const float* L_param   = (const float*)d_in[6];
  const float* Dp        = (const float*)d_in[7];
  const float* rms_w     = (const float*)d_in[8];
  const float* out_proj_w= (const float*)d_in[9];
  const float* out_proj_b= (const float*)d_in[10];
  float* out = (float*)d_out;

  char* W = (char*)d_ws;
  size_t off = 0;
  auto alloc = [&](size_t bytes) { void* p = W + off; off = (off + bytes + 255) & ~(size_t)255; return p; };
  double*   cgd = (double*)  alloc((size_t)NHEAD * T_LEN * 8);
  float*    zx  = (float*)   alloc((size_t)T_LEN * PROJ * 4);
  float*    ybuf= (float*)   alloc((size_t)T_LEN * INTER * 4);
  float*    gbuf= (float*)   alloc((size_t)T_LEN * NHEAD * 4);
  float*    dtb = (float*)   alloc((size_t)T_LEN * NHEAD * 4);
  float*    Lsb = (float*)   alloc((size_t)T_LEN * NHEAD * NLVL * 4);
  ushort_t* hsb = (ushort_t*)alloc((size_t)T_LEN * HID * 2);
  ushort_t* Wib = (ushort_t*)alloc((size_t)PROJ * HID * 2);
  ushort_t* Wob = (ushort_t*)alloc((size_t)HID * INTER * 2);
  ushort_t* yhf = (ushort_t*)alloc((size_t)T_LEN * INTER * 2);
  ushort_t* vb  = (ushort_t*)alloc((size_t)T_LEN * INTER * 2);
  ushort_t* vt  = (ushort_t*)alloc((size_t)T_LEN * INTER * 2);
  ushort_t* Bb  = (ushort_t*)alloc((size_t)T_LEN * NSTATE * 2);
  ushort_t* Cb  = (ushort_t*)alloc((size_t)T_LEN * NSTATE * 2);

  // 0. f16 conversions
  f32_to_f16<<<(T_LEN * HID / 4 + 255) / 256, 256, 0, stream>>>(hs, hsb, T_LEN * HID / 4);
  f32_to_f16<<<(PROJ * HID / 4 + 255) / 256, 256, 0, stream>>>(in_proj_w, Wib, PROJ * HID / 4);
  f32_to_f16<<<(HID * INTER / 4 + 255) / 256, 256, 0, stream>>>(out_proj_w, Wob, HID * INTER / 4);

  // 1. in_proj: zx = hs @ W^T + b
  gemm_f16<<<dim3(PROJ / 128, T_LEN / 128), 256, 0, stream>>>(
      hsb, Wib, in_proj_b, zx, T_LEN, PROJ, HID);

  // 2. pointwise
  pointwise_dt<<<T_LEN, 512, 0, stream>>>(zx, dt_bias, A_log, L_param, dtb, gbuf, Lsb);

  // 3. conv + silu + split
  conv_silu<<<(T_LEN * CONV_DIM + 255) / 256, 256, 0, stream>>>(
      zx, conv_w, dtb, Dp, vb, ybuf, Bb, Cb);

  // 3b. transpose v -> vt[h*64+p][t]
  vtrans<<<dim3(T_LEN / 64, INTER / 64), 256, 0, stream>>>(vb, vt);

  // 4. fp64 cumsum
  scan_g<<<NHEAD, T_LEN, 0, stream>>>(gbuf, cgd);

  // 5. split-K MFMA attention (1280 blocks)
  attn_mfma<<<NHEAD * 40, 256, 0, stream>>>(Bb, Cb, vt, cgd, Lsb, ybuf);

  // 6. gated RMSNorm -> f16
  rmsnorm_gate<<<T_LEN, 256, 0, stream>>>(ybuf, zx, rms_w, yhf);

  // 7. out_proj
  gemm_f16<<<dim3(HID / 128, T_LEN / 128), 256, 0, stream>>>(
      yhf, Wob, out_proj_b, out, T_LEN, HID, INTER);
}

// Round 5
// 211.284 us; speedup vs baseline: 6.7450x; 1.1393x over previous
//
#include <hip/hip_runtime.h>
#include <hip/hip_bf16.h>
#include <math.h>

// ---------------- model constants ----------------
#define T_LEN 1024
#define HID 1024
#define NHEAD 32
#define HDIM 64         // P
#define NSTATE 128      // N
#define NLVL 15
#define KCONV 4
#define INTER 2048
#define CONV_DIM 2304   // INTER + 2*N
#define PROJ 4864       // INTER + CONV_DIM + H*(NL+1)
#define EPS 1e-5f

typedef __attribute__((ext_vector_type(8))) _Float16 half8;
typedef __attribute__((ext_vector_type(4))) float float4v;
typedef unsigned short ushort_t;

__device__ __forceinline__ float softplus_f(float x) {
  return fmaxf(x, 0.f) + log1pf(expf(-fabsf(x)));
}
__device__ __forceinline__ float silu_f(float x) {
  return x / (1.f + expf(-x));
}
__device__ __forceinline__ ushort_t f2h(float f) {
  union { _Float16 h; ushort_t u; } v;
  v.h = (_Float16)f;
  return v.u;
}
// async global->LDS 16B: lds dst must be wave-uniform base; lane i lands at base+i*16
__device__ __forceinline__ void gload_lds16(const void* g, void* l) {
  __builtin_amdgcn_global_load_lds(
      (const __attribute__((address_space(1))) void*)g,
      (__attribute__((address_space(3))) void*)l, 16, 0, 0);
}

// ---------------- f32 -> f16 bulk convert ----------------
__global__ __launch_bounds__(256) void f32_to_f16(const float* __restrict__ src,
                                                  ushort_t* __restrict__ dst, int n4) {
  int i = blockIdx.x * 256 + threadIdx.x;
  if (i >= n4) return;
  float4 v = reinterpret_cast<const float4*>(src)[i];
  union { ushort_t u[4]; unsigned long long ll; } o;
  o.u[0] = f2h(v.x); o.u[1] = f2h(v.y); o.u[2] = f2h(v.z); o.u[3] = f2h(v.w);
  reinterpret_cast<unsigned long long*>(dst)[i] = o.ll;
}

// ---------------- split-K f16 MFMA GEMM (dbuf + global_load_lds) ----------------
// A:(M,K) f16, B:(N,K) f16. Partial chunk z writes Cpart[z][m][n] (f32, NO bias).
// Tile 128x128, BK=32, Kc per chunk. grid = (N/128, M/128, S).
__global__ __launch_bounds__(256) void gemm_f16_sk(
    const ushort_t* __restrict__ A, const ushort_t* __restrict__ B,
    float* __restrict__ Cpart, int M, int N, int K, int Kc) {
  __shared__ ushort_t As[2][128][32];   // 64B rows (no pad: global_load_lds layout)
  __shared__ ushort_t Bs[2][128][32];
  const int tid = threadIdx.x;
  const int w = tid >> 6, L = tid & 63;
  const int n0 = blockIdx.x * 128, m0 = blockIdx.y * 128;
  const int kbeg = blockIdx.z * Kc;
  float* __restrict__ C = Cpart + (size_t)blockIdx.z * M * N;
  const int mq = (w & 1) * 64, nq = (w >> 1) * 64;

  // per-lane source row/chunk for staging (lane L of wave w, instr j)
  const int srow = (L >> 2);        // 0..15 within 16-row group
  const int sch = (L & 3) * 8;      // k-offset in halfs

  float4v acc[4][4];
#pragma unroll
  for (int i = 0; i < 4; ++i)
#pragma unroll
    for (int j = 0; j < 4; ++j) acc[i][j] = (float4v){0.f, 0.f, 0.f, 0.f};

  const int niter = Kc / 32;
  // prologue: stage tile 0 into buf 0
  {
    const int kk = kbeg;
#pragma unroll
    for (int j = 0; j < 2; ++j) {
      int r0 = 16 * (w * 2 + j);
      gload_lds16(A + (size_t)(m0 + r0 + srow) * K + kk + sch, &As[0][r0][0]);
      gload_lds16(B + (size_t)(n0 + r0 + srow) * K + kk + sch, &Bs[0][r0][0]);
    }
  }
  for (int it = 0; it < niter; ++it) {
    __syncthreads();   // drains vmcnt: buf[it&1] ready; buf[it^1] free for writers
    if (it + 1 < niter) {
      const int kk = kbeg + (it + 1) * 32;
      const int nb = (it + 1) & 1;
#pragma unroll
      for (int j = 0; j < 2; ++j) {
        int r0 = 16 * (w * 2 + j);
        gload_lds16(A + (size_t)(m0 + r0 + srow) * K + kk + sch, &As[nb][r0][0]);
        gload_lds16(B + (size_t)(n0 + r0 + srow) * K + kk + sch, &Bs[nb][r0][0]);
      }
    }
    const int cb = it & 1;
    half8 af[4], bf[4];
#pragma unroll
    for (int t = 0; t < 4; ++t) {
      af[t] = *reinterpret_cast<const half8*>(&As[cb][mq + t * 16 + (L & 15)][(L >> 4) * 8]);
      bf[t] = *reinterpret_cast<const half8*>(&Bs[cb][nq + t * 16 + (L & 15)][(L >> 4) * 8]);
    }
#pragma unroll
    for (int mt = 0; mt < 4; ++mt)
#pragma unroll
      for (int nt = 0; nt < 4; ++nt)
        acc[mt][nt] = __builtin_amdgcn_mfma_f32_16x16x32_f16(af[mt], bf[nt], acc[mt][nt], 0, 0, 0);
  }
  const int qrow = (L >> 4) * 4;
#pragma unroll
  for (int mt = 0; mt < 4; ++mt) {
#pragma unroll
    for (int nt = 0; nt < 4; ++nt) {
      int col = n0 + nq + nt * 16 + (L & 15);
#pragma unroll
      for (int r = 0; r < 4; ++r) {
        int row = m0 + mq + mt * 16 + qrow + r;
        C[(size_t)row * N + col] = acc[mt][nt][r];
      }
    }
  }
}

// ---------------- reduce 4 out_proj partials + bias ----------------
__global__ __launch_bounds__(256) void reduce_out4(const float* __restrict__ p,
                                                   const float* __restrict__ bias,
                                                   float* __restrict__ out, int MN) {
  int i = blockIdx.x * 256 + threadIdx.x;   // float4 index
  if (i * 4 >= MN) return;
  float4 a = reinterpret_cast<const float4*>(p)[i];
  float4 b = reinterpret_cast<const float4*>(p + MN)[i];
  float4 c = reinterpret_cast<const float4*>(p + 2 * (size_t)MN)[i];
  float4 d = reinterpret_cast<const float4*>(p + 3 * (size_t)MN)[i];
  int col = (i * 4) & (HID - 1);
  float4 bv = *reinterpret_cast<const float4*>(bias + col);
  float4 o;
  o.x = a.x + b.x + c.x + d.x + bv.x;
  o.y = a.y + b.y + c.y + d.y + bv.y;
  o.z = a.z + b.z + c.z + d.z + bv.z;
  o.w = a.w + b.w + c.w + d.w + bv.w;
  reinterpret_cast<float4*>(out)[i] = o;
}

// ---------------- per-token pointwise: dt, g, level scales ----------------
__global__ __launch_bounds__(512) void pointwise_dt(
    const float* __restrict__ zx0, const float* __restrict__ zx1,
    const float* __restrict__ in_b, const float* __restrict__ dt_bias,
    const float* __restrict__ A_log, const float* __restrict__ L_param,
    float* __restrict__ dtbuf, float* __restrict__ gbuf,
    float* __restrict__ Lsbuf) {
  const int t = blockIdx.x;
  const int j = threadIdx.x;
  const size_t ro = (size_t)t * PROJ;
  if (j < NHEAD * NLVL) {
    int c = INTER + CONV_DIM + NHEAD + j;
    float x = L_param[j] * (zx0[ro + c] + zx1[ro + c] + in_b[c]);
    Lsbuf[(size_t)t * (NHEAD * NLVL) + j] = softplus_f(x);
  } else {
    int h = j - NHEAD * NLVL;
    int c = INTER + CONV_DIM + h;
    float x = zx0[ro + c] + zx1[ro + c] + in_b[c] + dt_bias[h];
    float dt = softplus_f(x);
    dtbuf[t * NHEAD + h] = dt;
    gbuf[t * NHEAD + h] = -expf(A_log[h]) * dt;
  }
}

// ---------------- depthwise causal conv (K=4) + SiLU + split ----------------
__global__ __launch_bounds__(256) void conv_silu(
    const float* __restrict__ zx0, const float* __restrict__ zx1,
    const float* __restrict__ in_b, const float* __restrict__ conv_w,
    const float* __restrict__ dtbuf, const float* __restrict__ Dp,
    ushort_t* __restrict__ vb, float* __restrict__ ybuf,
    ushort_t* __restrict__ Bb, ushort_t* __restrict__ Cb) {
  int idx = blockIdx.x * 256 + threadIdx.x;
  if (idx >= T_LEN * CONV_DIM) return;
  int t = idx / CONV_DIM;
  int c = idx - t * CONV_DIM;
  const float bc = in_b[INTER + c];
  float acc = 0.f;
#pragma unroll
  for (int w = 0; w < KCONV; ++w) {
    int tt = t - (KCONV - 1) + w;
    if (tt >= 0) {
      size_t o = (size_t)tt * PROJ + INTER + c;
      acc += (zx0[o] + zx1[o] + bc) * conv_w[c * KCONV + w];
    }
  }
  float sil = silu_f(acc);
  if (c < INTER) {
    int h = c >> 6;
    float dt = dtbuf[t * NHEAD + h];
    vb[(size_t)t * INTER + c] = f2h(sil * dt);    // v = x*dt (f16)
    ybuf[(size_t)t * INTER + c] = sil * Dp[h];    // D residual (f32)
  } else if (c < INTER + NSTATE) {
    Bb[t * NSTATE + (c - INTER)] = f2h(sil);
  } else {
    Cb[t * NSTATE + (c - INTER - NSTATE)] = f2h(sil);
  }
}

// ---------------- transpose v: vt[h*64+p][t] = vb[t][h*64+p] ----------------
__global__ __launch_bounds__(256) void vtrans(const ushort_t* __restrict__ vb,
                                              ushort_t* __restrict__ vt) {
  __shared__ ushort_t Tl[64][72];
  const int tid = threadIdx.x;
  const int t0 = blockIdx.x * 64, c0 = blockIdx.y * 64;
#pragma unroll
  for (int i = 0; i < 2; ++i) {
    int u = tid + 256 * i;
    int r = u >> 3, c8 = (u & 7) * 8;
    *reinterpret_cast<half8*>(&Tl[r][c8]) =
        *reinterpret_cast<const half8*>(vb + (size_t)(t0 + r) * INTER + c0 + c8);
  }
  __syncthreads();
#pragma unroll
  for (int i = 0; i < 2; ++i) {
    int u = tid + 256 * i;
    int p = u >> 3, t8 = (u & 7) * 8;
    union { ushort_t u16[8]; half8 h; } o;
#pragma unroll
    for (int j = 0; j < 8; ++j) o.u16[j] = Tl[t8 + j][p];
    *reinterpret_cast<half8*>(vt + (size_t)(c0 + p) * T_LEN + t0 + t8) = o.h;
  }
}

// ---------------- per-head inclusive cumsum of g (fp64) ----------------
__global__ __launch_bounds__(1024) void scan_g(const float* __restrict__ gbuf,
                                               double* __restrict__ cgd) {
  __shared__ double buf[T_LEN];
  const int h = blockIdx.x, t = threadIdx.x;
  buf[t] = (double)gbuf[t * NHEAD + h];
  __syncthreads();
  for (int off = 1; off < T_LEN; off <<= 1) {
    double v = buf[t];
    double a = (t >= off) ? buf[t - off] : 0.0;
    __syncthreads();
    buf[t] = v + a;
    __syncthreads();
  }
  cgd[(size_t)h * T_LEN + t] = buf[t];
}

// ---------------- split-K MFMA attention ----------------
__global__ __launch_bounds__(256) void attn_mfma(
    const ushort_t* __restrict__ Bb, const ushort_t* __restrict__ Cb,
    const ushort_t* __restrict__ vt, const double* __restrict__ cgd,
    const float* __restrict__ Lsb, float* __restrict__ ybuf) {
  __shared__ ushort_t Bl[64][136];
  __shared__ ushort_t Vtl[64][72];
  __shared__ ushort_t Sl[64][72];
  __shared__ float Lsl[64][17];
  __shared__ float cgq[64];
  __shared__ float cgs[64];

  const int item = blockIdx.x;
  const int h = item / 40;
  const int rem = item - h * 40;
  int qt, j;
  if (rem < 4)        { qt = rem;                 j = 0; }
  else if (rem < 12)  { qt = 4 + (rem - 4) / 2;   j = (rem - 4) % 2; }
  else if (rem < 24)  { qt = 8 + (rem - 12) / 3;  j = (rem - 12) % 3; }
  else                { qt = 12 + (rem - 24) / 4; j = (rem - 24) % 4; }

  const int tid = threadIdx.x;
  const int w = tid >> 6, L = tid & 63;
  const int tq0 = qt * 64;
  const double* cgh = cgd + (size_t)h * T_LEN;
  const double base = cgh[tq0];

  for (int i = tid; i < 64 * NLVL; i += 256) {
    int r = i / NLVL, l = i - r * NLVL;
    Lsl[r][l] = Lsb[(size_t)(tq0 + r) * (NHEAD * NLVL) + h * NLVL + l];
  }
  if (tid < 64) cgq[tid] = (float)(cgh[tq0 + tid] - base);

  half8 cfrag[4];
  {
    const ushort_t* cr = Cb + (size_t)(tq0 + w * 16 + (L & 15)) * NSTATE + (L >> 4) * 8;
#pragma unroll
    for (int ks = 0; ks < 4; ++ks)
      cfrag[ks] = *reinterpret_cast<const half8*>(cr + ks * 32);
  }
  float4v yac[4];
#pragma unroll
  for (int i = 0; i < 4; ++i) yac[i] = (float4v){0.f, 0.f, 0.f, 0.f};

  const int qrow = w * 16 + ((L >> 4) << 2);

  const int st0 = 4 * j;
  const int st1 = min(4 * j + 4, qt + 1);
  for (int st = st0; st < st1; ++st) {
    const int ts0 = st * 64;
    __syncthreads();
#pragma unroll
    for (int i = 0; i < 4; ++i) {
      int u = tid + 256 * i;
      int row = u >> 4, kb = (u & 15) * 8;
      *reinterpret_cast<half8*>(&Bl[row][kb]) =
          *reinterpret_cast<const half8*>(Bb + (size_t)(ts0 + row) * NSTATE + kb);
    }
#pragma unroll
    for (int i = 0; i < 2; ++i) {
      int u = tid + 256 * i;
      int p = u >> 3, sc = (u & 7) * 8;
      *reinterpret_cast<half8*>(&Vtl[p][sc]) =
          *reinterpret_cast<const half8*>(vt + (size_t)(h * HDIM + p) * T_LEN + ts0 + sc);
    }
    if (tid < 64) cgs[tid] = (float)(cgh[ts0 + tid] - base);
    __syncthreads();

    float4v sac[4];
#pragma unroll
    for (int nt = 0; nt < 4; ++nt) sac[nt] = (float4v){0.f, 0.f, 0.f, 0.f};
#pragma unroll
    for (int ks = 0; ks < 4; ++ks) {
#pragma unroll
      for (int nt = 0; nt < 4; ++nt) {
        half8 bfrag = *reinterpret_cast<const half8*>(&Bl[nt * 16 + (L & 15)][ks * 32 + (L >> 4) * 8]);
        sac[nt] = __builtin_amdgcn_mfma_f32_16x16x32_f16(cfrag[ks], bfrag, sac[nt], 0, 0, 0);
      }
    }
#pragma unroll
    for (int nt = 0; nt < 4; ++nt) {
      int s = nt * 16 + (L & 15);
      int sg = ts0 + s;
      float cs = cgs[s];
#pragma unroll
      for (int r = 0; r < 4; ++r) {
        int q = qrow + r;
        int tg = tq0 + q;
        float val = 0.f;
        if (sg <= tg) {
          int lvl = 31 - __clz((unsigned)(sg ^ (tg + 1)));
          val = sac[nt][r] * __expf(cgq[q] - cs) * Lsl[q][lvl];
        }
        Sl[q][s] = f2h(val);
      }
    }
    __builtin_amdgcn_s_waitcnt(0);
#pragma unroll
    for (int ks = 0; ks < 2; ++ks) {
      half8 af = *reinterpret_cast<const half8*>(&Sl[w * 16 + (L & 15)][ks * 32 + (L >> 4) * 8]);
#pragma unroll
      for (int pt = 0; pt < 4; ++pt) {
        half8 bfv = *reinterpret_cast<const half8*>(&Vtl[pt * 16 + (L & 15)][ks * 32 + (L >> 4) * 8]);
        yac[pt] = __builtin_amdgcn_mfma_f32_16x16x32_f16(af, bfv, yac[pt], 0, 0, 0);
      }
    }
  }
#pragma unroll
  for (int pt = 0; pt < 4; ++pt) {
    int p = pt * 16 + (L & 15);
#pragma unroll
    for (int r = 0; r < 4; ++r) {
      int q = qrow + r;
      atomicAdd(ybuf + (size_t)(tq0 + q) * INTER + h * HDIM + p, yac[pt][r]);
    }
  }
}

// ---------------- gated RMSNorm -> f16 ----------------
__global__ __launch_bounds__(256) void rmsnorm_gate(
    const float* __restrict__ ybuf, const float* __restrict__ zx0,
    const float* __restrict__ zx1, const float* __restrict__ in_b,
    const float* __restrict__ w, ushort_t* __restrict__ yhf) {
  __shared__ float red[4];
  const int t = blockIdx.x, tid = threadIdx.x;
  const size_t ro = (size_t)t * PROJ;
  const float* yrow = ybuf + (size_t)t * INTER;
  float yg[8];
  float ss = 0.f;
#pragma unroll
  for (int i = 0; i < 8; ++i) {
    int c = tid + 256 * i;
    float z = zx0[ro + c] + zx1[ro + c] + in_b[c];
    float g = yrow[c] * silu_f(z);
    yg[i] = g;
    ss += g * g;
  }
#pragma unroll
  for (int off = 32; off; off >>= 1) ss += __shfl_down(ss, off, 64);
  if ((tid & 63) == 0) red[tid >> 6] = ss;
  __syncthreads();
  if (tid == 0) red[0] = red[0] + red[1] + red[2] + red[3];
  __syncthreads();
  const float scale = rsqrtf(red[0] / (float)INTER + EPS);
#pragma unroll
  for (int i = 0; i < 8; ++i) {
    int c = tid + 256 * i;
    yhf[(size_t)t * INTER + c] = f2h(yg[i] * scale * w[c]);
  }
}

// ---------------- launch ----------------
extern "C" void kernel_launch(void* const* d_in, const int* in_sizes, int n_in,
                              void* d_out, int out_size, void* d_ws, size_t ws_size,
                              hipStream_t stream) {
  const float* hs        = (const float*)d_in[0];
  const float* in_proj_w = (const float*)d_in[1];
  const float* in_proj_b = (const float*)d_in[2];
  const float* conv_w    = (const float*)d_in[3];
  const float* dt_bias   = (const float*)d_in[4];
  const float* A_log     = (const float*)d_in[5];
  const float* L_param   = (const float*)d_in[6];
  const float* Dp        = (const float*)d_in[7];
  const float* rms_w     = (const float*)d_in[8];
  const float* out_proj_w= (const float*)d_in[9];
  const float* out_proj_b= (const float*)d_in[10];
  float* out = (float*)d_out;

  char* W = (char*)d_ws;
  size_t off = 0;
  auto alloc = [&](size_t bytes) { void* p = W + off; off = (off + bytes + 255) & ~(size_t)255; return p; };
  double*   cgd = (double*)  alloc((size_t)NHEAD * T_LEN * 8);
  float*    zx0 = (float*)   alloc((size_t)T_LEN * PROJ * 4);
  float*    zx1 = (float*)   alloc((size_t)T_LEN * PROJ * 4);
  float*    opp = (float*)   alloc((size_t)4 * T_LEN * HID * 4);   // out_proj partials
  float*    ybuf= (float*)   alloc((size_t)T_LEN * INTER * 4);
  float*    gbuf= (float*)   alloc((size_t)T_LEN * NHEAD * 4);
  float*    dtb = (float*)   alloc((size_t)T_LEN * NHEAD * 4);
  float*    Lsb = (float*)   alloc((size_t)T_LEN * NHEAD * NLVL * 4);
  ushort_t* hsb = (ushort_t*)alloc((size_t)T_LEN * HID * 2);
  ushort_t* Wib = (ushort_t*)alloc((size_t)PROJ * HID * 2);
  ushort_t* Wob = (ushort_t*)alloc((size_t)HID * INTER * 2);
  ushort_t* yhf = (ushort_t*)alloc((size_t)T_LEN * INTER * 2);
  ushort_t* vb  = (ushort_t*)alloc((size_t)T_LEN * INTER * 2);
  ushort_t* vt  = (ushort_t*)alloc((size_t)T_LEN * INTER * 2);
  ushort_t* Bb  = (ushort_t*)alloc((size_t)T_LEN * NSTATE * 2);
  ushort_t* Cb  = (ushort_t*)alloc((size_t)T_LEN * NSTATE * 2);

  // 0. f16 conversions
  f32_to_f16<<<(T_LEN * HID / 4 + 255) / 256, 256, 0, stream>>>(hs, hsb, T_LEN * HID / 4);
  f32_to_f16<<<(PROJ * HID / 4 + 255) / 256, 256, 0, stream>>>(in_proj_w, Wib, PROJ * HID / 4);
  f32_to_f16<<<(HID * INTER / 4 + 255) / 256, 256, 0, stream>>>(out_proj_w, Wob, HID * INTER / 4);

  // 1. in_proj split-K=2: zx0/zx1 partials (bias added by consumers)
  gemm_f16_sk<<<dim3(PROJ / 128, T_LEN / 128, 2), 256, 0, stream>>>(
      hsb, Wib, zx0, T_LEN, PROJ, HID, HID / 2);

  // 2. pointwise
  pointwise_dt<<<T_LEN, 512, 0, stream>>>(zx0, zx1, in_proj_b, dt_bias, A_log, L_param,
                                          dtb, gbuf, Lsb);

  // 3. conv + silu + split
  conv_silu<<<(T_LEN * CONV_DIM + 255) / 256, 256, 0, stream>>>(
      zx0, zx1, in_proj_b, conv_w, dtb, Dp, vb, ybuf, Bb, Cb);

  // 3b. transpose v -> vt
  vtrans<<<dim3(T_LEN / 64, INTER / 64), 256, 0, stream>>>(vb, vt);

  // 4. fp64 cumsum
  scan_g<<<NHEAD, T_LEN, 0, stream>>>(gbuf, cgd);

  // 5. split-K MFMA attention
  attn_mfma<<<NHEAD * 40, 256, 0, stream>>>(Bb, Cb, vt, cgd, Lsb, ybuf);

  // 6. gated RMSNorm -> f16
  rmsnorm_gate<<<T_LEN, 256, 0, stream>>>(ybuf, zx0, zx1, in_proj_b, rms_w, yhf);

  // 7. out_proj split-K=4 -> partials, then reduce(+bias)
  gemm_f16_sk<<<dim3(HID / 128, T_LEN / 128, 4), 256, 0, stream>>>(
      yhf, Wob, opp, T_LEN, HID, INTER, INTER / 4);
  reduce_out4<<<(T_LEN * HID / 4 + 255) / 256, 256, 0, stream>>>(
      opp, out_proj_b, out, T_LEN * HID);
}

// Round 6
// 200.236 us; speedup vs baseline: 7.1171x; 1.0552x over previous
//
#include <hip/hip_runtime.h>
#include <hip/hip_bf16.h>
#include <math.h>

// ---------------- model constants ----------------
#define T_LEN 1024
#define HID 1024
#define NHEAD 32
#define HDIM 64         // P
#define NSTATE 128      // N
#define NLVL 15
#define KCONV 4
#define INTER 2048
#define CONV_DIM 2304   // INTER + 2*N
#define PROJ 4864       // INTER + CONV_DIM + H*(NL+1)
#define EPS 1e-5f

typedef __attribute__((ext_vector_type(8))) _Float16 half8;
typedef __attribute__((ext_vector_type(4))) float float4v;
typedef unsigned short ushort_t;

__device__ __forceinline__ float softplus_f(float x) {
  return fmaxf(x, 0.f) + log1pf(expf(-fabsf(x)));
}
__device__ __forceinline__ float silu_f(float x) {
  return x / (1.f + expf(-x));
}
__device__ __forceinline__ ushort_t f2h(float f) {
  union { _Float16 h; ushort_t u; } v;
  v.h = (_Float16)f;
  return v.u;
}
// async global->LDS 16B: lds dst must be wave-uniform base; lane i lands at base+i*16
__device__ __forceinline__ void gload_lds16(const void* g, void* l) {
  __builtin_amdgcn_global_load_lds(
      (const __attribute__((address_space(1))) void*)g,
      (__attribute__((address_space(3))) void*)l, 16, 0, 0);
}

// ---------------- fused f32 -> f16 converts (hs, in_proj_w, out_proj_w) ----------------
#define N4_HS  (T_LEN * HID / 4)          // 262144
#define N4_WI  (PROJ * HID / 4)           // 1245184
#define N4_WO  (HID * INTER / 4)          // 524288
__global__ __launch_bounds__(256) void prep_f16(
    const float* __restrict__ hs, const float* __restrict__ wi,
    const float* __restrict__ wo, ushort_t* __restrict__ hsb,
    ushort_t* __restrict__ wib, ushort_t* __restrict__ wob) {
  int i = blockIdx.x * 256 + threadIdx.x;
  const float* src; ushort_t* dst; int j;
  if (i < N4_HS)              { src = hs; dst = hsb; j = i; }
  else if (i < N4_HS + N4_WI) { src = wi; dst = wib; j = i - N4_HS; }
  else                        { src = wo; dst = wob; j = i - N4_HS - N4_WI; }
  float4 v = reinterpret_cast<const float4*>(src)[j];
  union { ushort_t u[4]; unsigned long long ll; } o;
  o.u[0] = f2h(v.x); o.u[1] = f2h(v.y); o.u[2] = f2h(v.z); o.u[3] = f2h(v.w);
  reinterpret_cast<unsigned long long*>(dst)[j] = o.ll;
}

// ---------------- split-K f16 MFMA GEMM (dbuf + global_load_lds) ----------------
__global__ __launch_bounds__(256) void gemm_f16_sk(
    const ushort_t* __restrict__ A, const ushort_t* __restrict__ B,
    float* __restrict__ Cpart, int M, int N, int K, int Kc) {
  __shared__ ushort_t As[2][128][32];   // 64B rows (no pad: global_load_lds layout)
  __shared__ ushort_t Bs[2][128][32];
  const int tid = threadIdx.x;
  const int w = tid >> 6, L = tid & 63;
  const int n0 = blockIdx.x * 128, m0 = blockIdx.y * 128;
  const int kbeg = blockIdx.z * Kc;
  float* __restrict__ C = Cpart + (size_t)blockIdx.z * M * N;
  const int mq = (w & 1) * 64, nq = (w >> 1) * 64;
  const int srow = (L >> 2);
  const int sch = (L & 3) * 8;

  float4v acc[4][4];
#pragma unroll
  for (int i = 0; i < 4; ++i)
#pragma unroll
    for (int j = 0; j < 4; ++j) acc[i][j] = (float4v){0.f, 0.f, 0.f, 0.f};

  const int niter = Kc / 32;
  {
    const int kk = kbeg;
#pragma unroll
    for (int j = 0; j < 2; ++j) {
      int r0 = 16 * (w * 2 + j);
      gload_lds16(A + (size_t)(m0 + r0 + srow) * K + kk + sch, &As[0][r0][0]);
      gload_lds16(B + (size_t)(n0 + r0 + srow) * K + kk + sch, &Bs[0][r0][0]);
    }
  }
  for (int it = 0; it < niter; ++it) {
    __syncthreads();
    if (it + 1 < niter) {
      const int kk = kbeg + (it + 1) * 32;
      const int nb = (it + 1) & 1;
#pragma unroll
      for (int j = 0; j < 2; ++j) {
        int r0 = 16 * (w * 2 + j);
        gload_lds16(A + (size_t)(m0 + r0 + srow) * K + kk + sch, &As[nb][r0][0]);
        gload_lds16(B + (size_t)(n0 + r0 + srow) * K + kk + sch, &Bs[nb][r0][0]);
      }
    }
    const int cb = it & 1;
    half8 af[4], bf[4];
#pragma unroll
    for (int t = 0; t < 4; ++t) {
      af[t] = *reinterpret_cast<const half8*>(&As[cb][mq + t * 16 + (L & 15)][(L >> 4) * 8]);
      bf[t] = *reinterpret_cast<const half8*>(&Bs[cb][nq + t * 16 + (L & 15)][(L >> 4) * 8]);
    }
#pragma unroll
    for (int mt = 0; mt < 4; ++mt)
#pragma unroll
      for (int nt = 0; nt < 4; ++nt)
        acc[mt][nt] = __builtin_amdgcn_mfma_f32_16x16x32_f16(af[mt], bf[nt], acc[mt][nt], 0, 0, 0);
  }
  const int qrow = (L >> 4) * 4;
#pragma unroll
  for (int mt = 0; mt < 4; ++mt) {
#pragma unroll
    for (int nt = 0; nt < 4; ++nt) {
      int col = n0 + nq + nt * 16 + (L & 15);
#pragma unroll
      for (int r = 0; r < 4; ++r) {
        int row = m0 + mq + mt * 16 + qrow + r;
        C[(size_t)row * N + col] = acc[mt][nt][r];
      }
    }
  }
}

// ---------------- reduce 4 out_proj partials + bias ----------------
__global__ __launch_bounds__(256) void reduce_out4(const float* __restrict__ p,
                                                   const float* __restrict__ bias,
                                                   float* __restrict__ out, int MN) {
  int i = blockIdx.x * 256 + threadIdx.x;
  if (i * 4 >= MN) return;
  float4 a = reinterpret_cast<const float4*>(p)[i];
  float4 b = reinterpret_cast<const float4*>(p + MN)[i];
  float4 c = reinterpret_cast<const float4*>(p + 2 * (size_t)MN)[i];
  float4 d = reinterpret_cast<const float4*>(p + 3 * (size_t)MN)[i];
  int col = (i * 4) & (HID - 1);
  float4 bv = *reinterpret_cast<const float4*>(bias + col);
  float4 o;
  o.x = a.x + b.x + c.x + d.x + bv.x;
  o.y = a.y + b.y + c.y + d.y + bv.y;
  o.z = a.z + b.z + c.z + d.z + bv.z;
  o.w = a.w + b.w + c.w + d.w + bv.w;
  reinterpret_cast<float4*>(out)[i] = o;
}

// ---------------- per-token pointwise: dt, g (transposed), level scales ----------------
__global__ __launch_bounds__(512) void pointwise_dt(
    const float* __restrict__ zx0, const float* __restrict__ zx1,
    const float* __restrict__ in_b, const float* __restrict__ dt_bias,
    const float* __restrict__ A_log, const float* __restrict__ L_param,
    float* __restrict__ dtbuf, float* __restrict__ gT,
    float* __restrict__ Lsbuf) {
  const int t = blockIdx.x;
  const int j = threadIdx.x;
  const size_t ro = (size_t)t * PROJ;
  if (j < NHEAD * NLVL) {
    int c = INTER + CONV_DIM + NHEAD + j;
    float x = L_param[j] * (zx0[ro + c] + zx1[ro + c] + in_b[c]);
    Lsbuf[(size_t)t * (NHEAD * NLVL) + j] = softplus_f(x);
  } else {
    int h = j - NHEAD * NLVL;
    int c = INTER + CONV_DIM + h;
    float x = zx0[ro + c] + zx1[ro + c] + in_b[c] + dt_bias[h];
    float dt = softplus_f(x);
    dtbuf[t * NHEAD + h] = dt;
    gT[h * T_LEN + t] = -expf(A_log[h]) * dt;   // transposed for the scan
  }
}

// ---------------- per-head fp64 scan, wave-shuffle (no barriers) ----------------
// grid = 32 heads, block = 64 lanes; lane l owns t in [l*16, l*16+16)
__global__ __launch_bounds__(64) void scan_g(const float* __restrict__ gT,
                                             double* __restrict__ cgd) {
  const int h = blockIdx.x, l = threadIdx.x;
  const float* gr = gT + (size_t)h * T_LEN + l * 16;
  double pre[16];
  double acc = 0.0;
#pragma unroll
  for (int i = 0; i < 16; ++i) { acc += (double)gr[i]; pre[i] = acc; }
  double s = acc;
#pragma unroll
  for (int off = 1; off < 64; off <<= 1) {
    double o = __shfl_up(s, off, 64);
    if (l >= off) s += o;
  }
  const double base = s - acc;   // exclusive prefix of lane totals
  double* cr = cgd + (size_t)h * T_LEN + l * 16;
#pragma unroll
  for (int i = 0; i < 16; ++i) cr[i] = base + pre[i];
}

// ---------------- fused conv(K=4)+SiLU+split, with in-block V transpose ----------------
// grid (16 t-tiles, 36 c-tiles of 64). c-tile<32: v path (head = cy); else B/C.
__global__ __launch_bounds__(256) void conv_fused(
    const float* __restrict__ zx0, const float* __restrict__ zx1,
    const float* __restrict__ in_b, const float* __restrict__ conv_w,
    const float* __restrict__ dtbuf, const float* __restrict__ Dp,
    ushort_t* __restrict__ vt, float* __restrict__ ybuf,
    ushort_t* __restrict__ Bb, ushort_t* __restrict__ Cb) {
  __shared__ ushort_t Vl[64][68];
  __shared__ float dtl[64];
  const int tq = blockIdx.x, cy = blockIdx.y;
  const int t0 = tq * 64;
  const int tid = threadIdx.x;
  const int lane = tid & 63, g = tid >> 6;
  const bool vpath = (cy < 32);
  const int ccol = vpath ? cy * 64 + lane : INTER + (cy - 32) * 64 + lane;  // conv-dim idx
  const int zcol = INTER + ccol;
  float cw[KCONV];
#pragma unroll
  for (int w = 0; w < KCONV; ++w) cw[w] = conv_w[ccol * KCONV + w];
  const float bc = in_b[zcol];
  if (vpath && tid < 64) dtl[tid] = dtbuf[(t0 + tid) * NHEAD + cy];
  const float Dh = vpath ? Dp[cy] : 0.f;

  float xv[19];
#pragma unroll
  for (int i = 0; i < 19; ++i) {
    int tt = t0 + g * 16 - 3 + i;
    if (tt >= 0) {
      size_t o = (size_t)tt * PROJ + zcol;
      xv[i] = zx0[o] + zx1[o] + bc;
    } else xv[i] = 0.f;
  }
  __syncthreads();   // dtl ready
#pragma unroll
  for (int i = 0; i < 16; ++i) {
    float acc = xv[i] * cw[0] + xv[i + 1] * cw[1] + xv[i + 2] * cw[2] + xv[i + 3] * cw[3];
    float sil = silu_f(acc);
    int tl = g * 16 + i;
    int t = t0 + tl;
    if (vpath) {
      ushort_t vh = f2h(sil * dtl[tl]);
      Vl[tl][lane] = vh;                                       // for transpose
      ybuf[(size_t)t * INTER + cy * 64 + lane] = sil * Dh;     // D residual
    } else if (ccol < INTER + NSTATE) {
      Bb[t * NSTATE + (ccol - INTER)] = f2h(sil);
    } else {
      Cb[t * NSTATE + (ccol - INTER - NSTATE)] = f2h(sil);
    }
  }
  if (vpath) {
    __syncthreads();
#pragma unroll
    for (int rep = 0; rep < 2; ++rep) {
      int u = tid + 256 * rep;
      int p = u >> 3, t8 = (u & 7) * 8;
      union { ushort_t u16[8]; half8 h; } o;
#pragma unroll
      for (int j = 0; j < 8; ++j) o.u16[j] = Vl[t8 + j][p];
      *reinterpret_cast<half8*>(vt + (size_t)(cy * 64 + p) * T_LEN + t0 + t8) = o.h;
    }
  }
}

// ---------------- split-K MFMA attention ----------------
__global__ __launch_bounds__(256) void attn_mfma(
    const ushort_t* __restrict__ Bb, const ushort_t* __restrict__ Cb,
    const ushort_t* __restrict__ vt, const double* __restrict__ cgd,
    const float* __restrict__ Lsb, float* __restrict__ ybuf) {
  __shared__ ushort_t Bl[64][136];
  __shared__ ushort_t Vtl[64][72];
  __shared__ ushort_t Sl[64][72];
  __shared__ float Lsl[64][16];
  __shared__ float cgq[64];
  __shared__ float cgs[64];

  const int item = blockIdx.x;
  const int h = item / 40;
  const int rem = item - h * 40;
  int qt, j;
  if (rem < 4)        { qt = rem;                 j = 0; }
  else if (rem < 12)  { qt = 4 + (rem - 4) / 2;   j = (rem - 4) % 2; }
  else if (rem < 24)  { qt = 8 + (rem - 12) / 3;  j = (rem - 12) % 3; }
  else                { qt = 12 + (rem - 24) / 4; j = (rem - 24) % 4; }

  const int tid = threadIdx.x;
  const int w = tid >> 6, L = tid & 63;
  const int tq0 = qt * 64;
  const double* cgh = cgd + (size_t)h * T_LEN;
  const double base = cgh[tq0];

  for (int i = tid; i < 64 * NLVL; i += 256) {
    int r = i / NLVL, l = i - r * NLVL;
    Lsl[r][l] = Lsb[(size_t)(tq0 + r) * (NHEAD * NLVL) + h * NLVL + l];
  }
  if (tid < 64) cgq[tid] = (float)(cgh[tq0 + tid] - base);

  half8 cfrag[4];
  {
    const ushort_t* cr = Cb + (size_t)(tq0 + w * 16 + (L & 15)) * NSTATE + (L >> 4) * 8;
#pragma unroll
    for (int ks = 0; ks < 4; ++ks)
      cfrag[ks] = *reinterpret_cast<const half8*>(cr + ks * 32);
  }
  float4v yac[4];
#pragma unroll
  for (int i = 0; i < 4; ++i) yac[i] = (float4v){0.f, 0.f, 0.f, 0.f};

  const int qrow = w * 16 + ((L >> 4) << 2);

  const int st0 = 4 * j;
  const int st1 = min(4 * j + 4, qt + 1);
  for (int st = st0; st < st1; ++st) {
    const int ts0 = st * 64;
    __syncthreads();
#pragma unroll
    for (int i = 0; i < 4; ++i) {
      int u = tid + 256 * i;
      int row = u >> 4, kb = (u & 15) * 8;
      *reinterpret_cast<half8*>(&Bl[row][kb]) =
          *reinterpret_cast<const half8*>(Bb + (size_t)(ts0 + row) * NSTATE + kb);
    }
#pragma unroll
    for (int i = 0; i < 2; ++i) {
      int u = tid + 256 * i;
      int p = u >> 3, sc = (u & 7) * 8;
      *reinterpret_cast<half8*>(&Vtl[p][sc]) =
          *reinterpret_cast<const half8*>(vt + (size_t)(h * HDIM + p) * T_LEN + ts0 + sc);
    }
    if (tid < 64) cgs[tid] = (float)(cgh[ts0 + tid] - base);
    __syncthreads();

    float4v sac[4];
#pragma unroll
    for (int nt = 0; nt < 4; ++nt) sac[nt] = (float4v){0.f, 0.f, 0.f, 0.f};
#pragma unroll
    for (int ks = 0; ks < 4; ++ks) {
#pragma unroll
      for (int nt = 0; nt < 4; ++nt) {
        half8 bfrag = *reinterpret_cast<const half8*>(&Bl[nt * 16 + (L & 15)][ks * 32 + (L >> 4) * 8]);
        sac[nt] = __builtin_amdgcn_mfma_f32_16x16x32_f16(cfrag[ks], bfrag, sac[nt], 0, 0, 0);
      }
    }
#pragma unroll
    for (int nt = 0; nt < 4; ++nt) {
      int s = nt * 16 + (L & 15);
      int sg = ts0 + s;
      float cs = cgs[s];
#pragma unroll
      for (int r = 0; r < 4; ++r) {
        int q = qrow + r;
        int tg = tq0 + q;
        float val = 0.f;
        if (sg <= tg) {
          int lvl = 31 - __clz((unsigned)(sg ^ (tg + 1)));
          val = sac[nt][r] * __expf(cgq[q] - cs) * Lsl[q][lvl];
        }
        Sl[q][s] = f2h(val);
      }
    }
    __builtin_amdgcn_s_waitcnt(0);
#pragma unroll
    for (int ks = 0; ks < 2; ++ks) {
      half8 af = *reinterpret_cast<const half8*>(&Sl[w * 16 + (L & 15)][ks * 32 + (L >> 4) * 8]);
#pragma unroll
      for (int pt = 0; pt < 4; ++pt) {
        half8 bfv = *reinterpret_cast<const half8*>(&Vtl[pt * 16 + (L & 15)][ks * 32 + (L >> 4) * 8]);
        yac[pt] = __builtin_amdgcn_mfma_f32_16x16x32_f16(af, bfv, yac[pt], 0, 0, 0);
      }
    }
  }
#pragma unroll
  for (int pt = 0; pt < 4; ++pt) {
    int p = pt * 16 + (L & 15);
#pragma unroll
    for (int r = 0; r < 4; ++r) {
      int q = qrow + r;
      atomicAdd(ybuf + (size_t)(tq0 + q) * INTER + h * HDIM + p, yac[pt][r]);
    }
  }
}

// ---------------- gated RMSNorm -> f16 ----------------
__global__ __launch_bounds__(256) void rmsnorm_gate(
    const float* __restrict__ ybuf, const float* __restrict__ zx0,
    const float* __restrict__ zx1, const float* __restrict__ in_b,
    const float* __restrict__ w, ushort_t* __restrict__ yhf) {
  __shared__ float red[4];
  const int t = blockIdx.x, tid = threadIdx.x;
  const size_t ro = (size_t)t * PROJ;
  const float* yrow = ybuf + (size_t)t * INTER;
  float yg[8];
  float ss = 0.f;
#pragma unroll
  for (int i = 0; i < 8; ++i) {
    int c = tid + 256 * i;
    float z = zx0[ro + c] + zx1[ro + c] + in_b[c];
    float g = yrow[c] * silu_f(z);
    yg[i] = g;
    ss += g * g;
  }
#pragma unroll
  for (int off = 32; off; off >>= 1) ss += __shfl_down(ss, off, 64);
  if ((tid & 63) == 0) red[tid >> 6] = ss;
  __syncthreads();
  if (tid == 0) red[0] = red[0] + red[1] + red[2] + red[3];
  __syncthreads();
  const float scale = rsqrtf(red[0] / (float)INTER + EPS);
#pragma unroll
  for (int i = 0; i < 8; ++i) {
    int c = tid + 256 * i;
    yhf[(size_t)t * INTER + c] = f2h(yg[i] * scale * w[c]);
  }
}

// ---------------- launch ----------------
extern "C" void kernel_launch(void* const* d_in, const int* in_sizes, int n_in,
                              void* d_out, int out_size, void* d_ws, size_t ws_size,
                              hipStream_t stream) {
  const float* hs        = (const float*)d_in[0];
  const float* in_proj_w = (const float*)d_in[1];
  const float* in_proj_b = (const float*)d_in[2];
  const float* conv_w    = (const float*)d_in[3];
  const float* dt_bias   = (const float*)d_in[4];
  const float* A_log     = (const float*)d_in[5];
  const float* L_param   = (const float*)d_in[6];
  const float* Dp        = (const float*)d_in[7];
  const float* rms_w     = (const float*)d_in[8];
  const float* out_proj_w= (const float*)d_in[9];
  const float* out_proj_b= (const float*)d_in[10];
  float* out = (float*)d_out;

  char* W = (char*)d_ws;
  size_t off = 0;
  auto alloc = [&](size_t bytes) { void* p = W + off; off = (off + bytes + 255) & ~(size_t)255; return p; };
  double*   cgd = (double*)  alloc((size_t)NHEAD * T_LEN * 8);
  float*    zx0 = (float*)   alloc((size_t)T_LEN * PROJ * 4);
  float*    zx1 = (float*)   alloc((size_t)T_LEN * PROJ * 4);
  float*    opp = (float*)   alloc((size_t)4 * T_LEN * HID * 4);
  float*    ybuf= (float*)   alloc((size_t)T_LEN * INTER * 4);
  float*    gT  = (float*)   alloc((size_t)NHEAD * T_LEN * 4);
  float*    dtb = (float*)   alloc((size_t)T_LEN * NHEAD * 4);
  float*    Lsb = (float*)   alloc((size_t)T_LEN * NHEAD * NLVL * 4);
  ushort_t* hsb = (ushort_t*)alloc((size_t)T_LEN * HID * 2);
  ushort_t* Wib = (ushort_t*)alloc((size_t)PROJ * HID * 2);
  ushort_t* Wob = (ushort_t*)alloc((size_t)HID * INTER * 2);
  ushort_t* yhf = (ushort_t*)alloc((size_t)T_LEN * INTER * 2);
  ushort_t* vt  = (ushort_t*)alloc((size_t)T_LEN * INTER * 2);
  ushort_t* Bb  = (ushort_t*)alloc((size_t)T_LEN * NSTATE * 2);
  ushort_t* Cb  = (ushort_t*)alloc((size_t)T_LEN * NSTATE * 2);

  // 1. fused f32->f16 conversions (hs, in_proj_w, out_proj_w)
  prep_f16<<<(N4_HS + N4_WI + N4_WO) / 256, 256, 0, stream>>>(
      hs, in_proj_w, out_proj_w, hsb, Wib, Wob);

  // 2. in_proj split-K=2: zx0/zx1 partials (bias folded in consumers)
  gemm_f16_sk<<<dim3(PROJ / 128, T_LEN / 128, 2), 256, 0, stream>>>(
      hsb, Wib, zx0, T_LEN, PROJ, HID, HID / 2);

  // 3. pointwise (g written transposed)
  pointwise_dt<<<T_LEN, 512, 0, stream>>>(zx0, zx1, in_proj_b, dt_bias, A_log, L_param,
                                          dtb, gT, Lsb);

  // 4. fp64 wave-shuffle scan
  scan_g<<<NHEAD, 64, 0, stream>>>(gT, cgd);

  // 5. fused conv + silu + split + V transpose
  conv_fused<<<dim3(T_LEN / 64, 36), 256, 0, stream>>>(
      zx0, zx1, in_proj_b, conv_w, dtb, Dp, vt, ybuf, Bb, Cb);

  // 6. split-K MFMA attention
  attn_mfma<<<NHEAD * 40, 256, 0, stream>>>(Bb, Cb, vt, cgd, Lsb, ybuf);

  // 7. gated RMSNorm -> f16
  rmsnorm_gate<<<T_LEN, 256, 0, stream>>>(ybuf, zx0, zx1, in_proj_b, rms_w, yhf);

  // 8. out_proj split-K=4 -> partials, then reduce(+bias)
  gemm_f16_sk<<<dim3(HID / 128, T_LEN / 128, 4), 256, 0, stream>>>(
      yhf, Wob, opp, T_LEN, HID, INTER, INTER / 4);
  reduce_out4<<<(T_LEN * HID / 4 + 255) / 256, 256, 0, stream>>>(
      opp, out_proj_b, out, T_LEN * HID);
}